// Round 2
// 3013.448 us; speedup vs baseline: 1.7004x; 1.7004x over previous
//
#include <hip/hip_runtime.h>

typedef unsigned short u16;
typedef short bf16x8 __attribute__((ext_vector_type(8)));
typedef float f32x4 __attribute__((ext_vector_type(4)));

#define NTOK 32768
#define LC 512            // L-chunk for U/scan
#define NCH 8             // 4096 / LC
#define MC 8192           // token chunk for FFN
#define NFC 4             // 32768 / MC

// workspace offsets (bytes)
#define OFF_XB     0ull              // 64 MiB  bf16 x  -> later A1
#define OFF_CNNB   67108864ull       // 64 MiB  cnn bf16 -> later T1c(32M)+A2c(32M)
#define OFF_XNB    134217728ull      // 64 MiB  xn bf16 -> blend (in place)
#define OFF_U4C    201326592ull      // 32 MiB  Uc chunk [r][3072] bf16 (24M used)
#define OFF_WCT    234881024ull      // 8 MiB
#define OFF_WSRUT  243269632ull      // 6 MiB
#define OFF_W1T    249561088ull      // 4 MiB
#define OFF_W2T    253755392ull      // 4 MiB
#define OFF_CARRY  257949696ull      // 32 KiB f32[8192]
#define OFF_P      257982464ull      // 64 KiB param block f32[16384]
#define OFF_SCALE  258048000ull      // 128 KiB f32[32768]
#define OFF_FLAG   258179072ull      // int
#define OFF_ZERO   258179328ull      // 128 B zero pad for im2col OOB lanes
#define WS_REQ     258183168ull

// param-block offsets (floats)
#define P_CONVB 0
#define P_LNW   1024
#define P_LNB   2048
#define P_VF    3072
#define P_VR    4096
#define P_BF    5120
#define P_BR    6144
#define P_LAM   7168
#define P_RMS   8192
#define P_LN1W  9216
#define P_LN1B  10240
#define P_LIN2B 11264
#define P_LN2W  12288
#define P_LN2B  14336

__device__ __forceinline__ float b2f(u16 u) {
    union { unsigned int i; float f; } v; v.i = ((unsigned int)u) << 16; return v.f;
}
__device__ __forceinline__ u16 f2b(float f) {
    union { float f; unsigned int i; } v; v.f = f;
    unsigned int r = v.i + 0x7fffu + ((v.i >> 16) & 1u);
    return (u16)(r >> 16);
}
__device__ __forceinline__ float ldp(const void* p, size_t i, int fl) {
    return fl ? ((const float*)p)[i] : b2f(((const u16*)p)[i]);
}
__device__ __forceinline__ float gelu_exact(float a) {
    return 0.5f * a * (1.0f + erff(a * 0.70710678118654752f));
}

// async global->LDS, 16B per lane; dest = wave-uniform base + lane*16
typedef const __attribute__((address_space(1))) void gas_void;
typedef __attribute__((address_space(3))) void las_void;
__device__ __forceinline__ void gl16(const u16* g, u16* l) {
    __builtin_amdgcn_global_load_lds((gas_void*)g, (las_void*)l, 16, 0, 0);
}

// k-group XOR swizzle: LDS[row][c] holds global k-group (c ^ f(row)).
// f(row) = (row + (row>>3)) & 3  -> 2-way max bank aliasing on frag ds_read_b128.
__device__ __forceinline__ int kswz(int row) { return (row + (row >> 3)) & 3; }

// ------------------------------------------------------------------
__global__ __launch_bounds__(256) void k_fill(float* out, float v) {
    size_t i = ((size_t)blockIdx.x * 256 + threadIdx.x) * 4;
    float4 o; o.x = v; o.y = v; o.z = v; o.w = v;
    *(float4*)(out + i) = o;
}

// dtype detect: for f32 data the EVEN u16 of each pair is the low mantissa
// half -> random bits -> wild exponents/NaN when read as bf16.
__global__ void k_detect(const u16* __restrict__ x, int* __restrict__ flag) {
    __shared__ int cnt[4];
    int tid = threadIdx.x;
    int c = 0;
    for (int i = 0; i < 16; ++i) {
        float f = b2f(x[2 * (tid * 16 + i)]);
        if (f != f || fabsf(f) > 1e6f) c++;
    }
    #pragma unroll
    for (int m = 32; m; m >>= 1) c += __shfl_xor(c, m, 64);
    if ((tid & 63) == 0) cnt[tid >> 6] = c;
    __syncthreads();
    if (tid == 0) flag[0] = (cnt[0] + cnt[1] + cnt[2] + cnt[3] > 100) ? 1 : 0;
}

__global__ __launch_bounds__(256) void k_params(const int* __restrict__ flag,
        const void* conv_b, const void* lnw, const void* lnb,
        const void* vf, const void* vr, const void* bf, const void* br,
        const void* lam, const void* rms, const void* ln1w, const void* ln1b,
        const void* lin2b, const void* ln2w, const void* ln2b,
        float* __restrict__ P, float* __restrict__ Z) {
    if (blockIdx.x == 0 && threadIdx.x < 32) Z[threadIdx.x] = 0.0f;
    int idx = blockIdx.x * 256 + threadIdx.x;   // 0..16383
    int fl = flag[0];
    int vec = idx >> 10, off = idx & 1023;
    const void* src; size_t so = off;
    switch (vec) {
        case 0: src = conv_b; break;
        case 1: src = lnw; break;
        case 2: src = lnb; break;
        case 3: src = vf; break;
        case 4: src = vr; break;
        case 5: src = bf; break;
        case 6: src = br; break;
        case 7: src = lam; break;
        case 8: src = rms; break;
        case 9: src = ln1w; break;
        case 10: src = ln1b; break;
        case 11: src = lin2b; break;
        case 12: case 13: src = ln2w; so = idx - P_LN2W; break;
        default: src = ln2b; so = idx - P_LN2B; break;
    }
    P[idx] = ldp(src, so, fl);
}

__global__ __launch_bounds__(256) void k_x2b(const int* __restrict__ flag,
                                             const void* __restrict__ x, u16* __restrict__ xb) {
    size_t i = (size_t)blockIdx.x * 256 + threadIdx.x;
    int fl = flag[0];
    ushort4 o;
    if (fl) {
        float4 v = ((const float4*)x)[i];
        o.x = f2b(v.x); o.y = f2b(v.y); o.z = f2b(v.z); o.w = f2b(v.w);
    } else {
        o = ((const ushort4*)x)[i];
    }
    ((ushort4*)xb)[i] = o;
}

// conv_w (O,I,K=4) -> WcT[o][k*1024+i] bf16
__global__ __launch_bounds__(256) void k_conv_reorder(const int* __restrict__ flag,
                                                      const void* __restrict__ w, u16* __restrict__ out) {
    int o = blockIdx.x, fl = flag[0];
    for (int kk = threadIdx.x; kk < 4096; kk += 256) {
        int k = kk >> 10, i = kk & 1023;
        out[(size_t)o * 4096 + kk] = f2b(ldp(w, (size_t)o * 4096 + i * 4 + k, fl));
    }
}

__global__ __launch_bounds__(256) void k_transpose(const int* __restrict__ flag,
                                                   const void* __restrict__ in, u16* __restrict__ out,
                                                   int R, int C) {
    int n = blockIdx.x, fl = flag[0];
    for (int r = threadIdx.x; r < R; r += 256)
        out[(size_t)n * R + r] = f2b(ldp(in, (size_t)r * C + n, fl));
}

// ------------------------------------------------------------------
// GEMM C[M,N]=A[M,K]*Bt[N,K]^T, bf16 MFMA 16x16x32, 128x128 tile, BK=32.
// m97 structure: global_load_lds(16B) staging, linear (k-group-XOR-swizzled)
// LDS, 2 barriers/K-step, XCD-chunked bijective block swizzle.
// MODE 0: plain A rows. MODE 1: conv im2col; per-batch row slice is contiguous
//   (base=(b*4096+l-3)*1024+k); taps with l+tap<3 read a 64B zero pad.
// MODE 2: chunked-U row remap token=((row>>9)<<12)+l0+(row&511).
// EPI 0: bf16 out. EPI 1: +P[conv_b] bf16. EPI 3: + lin2_b + gated residual.
template<int MODE, int EPI>
__global__ __launch_bounds__(256) void k_gemm(const u16* __restrict__ A, const u16* __restrict__ Bt,
                                              int N, int K, int nn, int l0, int tok0,
                                              const float* __restrict__ P,
                                              const u16* __restrict__ blend,
                                              const void* __restrict__ xorig,
                                              const float* __restrict__ scale,
                                              const int* __restrict__ flag,
                                              const u16* __restrict__ zb,
                                              void* __restrict__ outp) {
    __shared__ __align__(16) u16 As[128 * 32];
    __shared__ __align__(16) u16 Bs[128 * 32];
    const int tid = threadIdx.x;
    const int lane = tid & 63, wid = tid >> 6;
    const int wm = wid >> 1, wn = wid & 1;

    // XCD-chunked bijective swizzle (m204): consecutive swz share the A panel
    // and land on one XCD (dispatch round-robins bid%8 across XCDs).
    const int nwg = gridDim.x, bid = blockIdx.x;
    const int q = nwg >> 3, r = nwg & 7;
    const int xcd = bid & 7, idx = bid >> 3;
    const int swz = idx + (xcd < r ? xcd * (q + 1) : r * (q + 1) + (xcd - r) * q);
    const int mi = swz / nn, ni = swz - mi * nn;
    const int m0 = mi << 7, n0 = ni << 7;

    // staging: issue j in {0,1}: s = tid+256j; dest byte s*16 = LDS[s>>2][(s&3)*16B];
    // source k-group pre-XORed so reads can XOR the same pattern (rule #21).
    const u16* pa[2]; const u16* pb[2]; int kmin[2];
    u16 *la[2], *lb[2];
    #pragma unroll
    for (int j = 0; j < 2; ++j) {
        int s = tid + j * 256;
        int row = s >> 2;
        int kg = ((s & 3) ^ kswz(row)) << 3;
        la[j] = As + ((s & ~63) << 3);
        lb[j] = Bs + ((s & ~63) << 3);
        pb[j] = Bt + (size_t)(n0 + row) * K + kg;
        kmin[j] = 0;
        if (MODE == 1) {
            int t = m0 + row, b = t >> 12, l = t & 4095;
            pa[j] = A + (((size_t)(b << 12) + (size_t)(l - 3)) << 10) + kg;
            kmin[j] = (3 - l) << 10;            // k0 < kmin -> tap reads zero pad
        } else if (MODE == 2) {
            int rg = m0 + row;
            int token = ((rg >> 9) << 12) + l0 + (rg & 511);
            pa[j] = A + ((size_t)token << 10) + kg;
        } else {
            pa[j] = A + (size_t)(m0 + row) * K + kg;
        }
    }

    f32x4 acc[4][4];
    #pragma unroll
    for (int a = 0; a < 4; ++a)
        #pragma unroll
        for (int b = 0; b < 4; ++b)
            #pragma unroll
            for (int rr = 0; rr < 4; ++rr) acc[a][b][rr] = 0.0f;

    // fragment ds_read offsets (u16 units), XOR matching the staging swizzle
    int ra[4], rb[4];
    #pragma unroll
    for (int sm = 0; sm < 4; ++sm) {
        int rowa = wm * 64 + sm * 16 + (lane & 15);
        int rowb = wn * 64 + sm * 16 + (lane & 15);
        ra[sm] = (rowa << 5) + ((((lane >> 4) ^ kswz(rowa)) & 3) << 3);
        rb[sm] = (rowb << 5) + ((((lane >> 4) ^ kswz(rowb)) & 3) << 3);
    }

    const int nkb = K >> 5;
    for (int kb = 0; kb < nkb; ++kb) {
        const int k0 = kb << 5;
        __syncthreads();                         // prev iter's LDS reads done
        #pragma unroll
        for (int j = 0; j < 2; ++j) {
            const u16* ga = pa[j] + k0;
            if (MODE == 1) ga = (k0 < kmin[j]) ? zb : ga;
            gl16(ga, la[j]);
            gl16(pb[j] + k0, lb[j]);
        }
        __syncthreads();                         // barrier drains vmcnt -> tile ready

        bf16x8 af[4], bfr[4];
        #pragma unroll
        for (int sm = 0; sm < 4; ++sm) af[sm] = *(const bf16x8*)(As + ra[sm]);
        #pragma unroll
        for (int sn = 0; sn < 4; ++sn) bfr[sn] = *(const bf16x8*)(Bs + rb[sn]);
        #pragma unroll
        for (int sm = 0; sm < 4; ++sm)
            #pragma unroll
            for (int sn = 0; sn < 4; ++sn)
                acc[sm][sn] = __builtin_amdgcn_mfma_f32_16x16x32_bf16(af[sm], bfr[sn], acc[sm][sn], 0, 0, 0);
    }

    int fl = 0;
    if (EPI == 3) fl = flag[0];
    // C/D layout: col=lane&15, row=(lane>>4)*4+reg
    #pragma unroll
    for (int sm = 0; sm < 4; ++sm) {
        #pragma unroll
        for (int sn = 0; sn < 4; ++sn) {
            int rbase = m0 + wm * 64 + sm * 16 + ((lane >> 4) * 4);
            int col   = n0 + wn * 64 + sn * 16 + (lane & 15);
            #pragma unroll
            for (int rr = 0; rr < 4; ++rr) {
                int rowg = rbase + rr;
                float v = acc[sm][sn][rr];
                if (EPI == 0) {
                    ((u16*)outp)[(size_t)rowg * N + col] = f2b(v);
                } else if (EPI == 1) {
                    ((u16*)outp)[(size_t)rowg * N + col] = f2b(v + P[P_CONVB + col]);
                } else {
                    size_t gi = ((size_t)(tok0 + rowg) << 10) + col;
                    float xv = ldp(xorig, gi, fl);
                    float g = b2f(blend[gi]) * scale[tok0 + rowg] * P[P_RMS + col] * xv;
                    float o = v + P[P_LIN2B + col] + g;
                    if (fl) ((float*)outp)[gi] = o;
                    else    ((u16*)outp)[gi] = f2b(o);
                }
            }
        }
    }
}

// ------------------------------------------------------------------
__device__ __forceinline__ void breduce2(float& a, float& b, volatile float* sa, volatile float* sb, int tid) {
    #pragma unroll
    for (int m = 32; m; m >>= 1) { a += __shfl_xor(a, m, 64); b += __shfl_xor(b, m, 64); }
    int lane = tid & 63, wid = tid >> 6;
    if (lane == 0) { sa[wid] = a; sb[wid] = b; }
    __syncthreads();
    a = sa[0] + sa[1] + sa[2] + sa[3];
    b = sb[0] + sb[1] + sb[2] + sb[3];
    __syncthreads();
}

__global__ __launch_bounds__(256) void k_ln(const u16* __restrict__ cnnb, const float* __restrict__ P,
                                            u16* __restrict__ xnb) {
    __shared__ float sred[8];
    int t = blockIdx.x, tid = threadIdx.x;
    ushort4 cv = ((const ushort4*)(cnnb + ((size_t)t << 10)))[tid];
    float v0 = b2f(cv.x), v1 = b2f(cv.y), v2 = b2f(cv.z), v3 = b2f(cv.w);
    float s = v0 + v1 + v2 + v3;
    float ss = v0 * v0 + v1 * v1 + v2 * v2 + v3 * v3;
    breduce2(s, ss, sred, sred + 4, tid);
    float m = s * (1.0f / 1024.0f);
    float var = ss * (1.0f / 1024.0f) - m * m;
    float rs = rsqrtf(var + 1e-5f);
    int c = tid * 4;
    ushort4 o;
    o.x = f2b((v0 - m) * rs * P[P_LNW + c + 0] + P[P_LNB + c + 0]);
    o.y = f2b((v1 - m) * rs * P[P_LNW + c + 1] + P[P_LNB + c + 1]);
    o.z = f2b((v2 - m) * rs * P[P_LNW + c + 2] + P[P_LNB + c + 2]);
    o.w = f2b((v3 - m) * rs * P[P_LNW + c + 3] + P[P_LNB + c + 3]);
    ((ushort4*)(xnb + ((size_t)t << 10)))[tid] = o;
}

// ------------------------------------------------------------------
// SRU scan; Uc is [r][3072] bf16 (planes u0/u1/u2 at col 0/1024/2048)
__global__ __launch_bounds__(256) void k_scan(const u16* __restrict__ Uc, const u16* __restrict__ cnnb,
                                              u16* xnblend, float* __restrict__ carry,
                                              const float* __restrict__ P, int l0, int first) {
    int h = blockIdx.x * 256 + threadIdx.x;   // 0..1023
    int b = blockIdx.y;
    float vfv = P[P_VF + h], vrv = P[P_VR + h], bfv = P[P_BF + h], brv = P[P_BR + h], lamv = P[P_LAM + h];
    const float SXC = 1.00911627f;            // sqrt(1+exp(-4))
    float c = first ? 0.0f : carry[(b << 10) + h];
    size_t ub = (size_t)b * 512 * 3072 + h;
    size_t gbase = (((size_t)(b * 4096 + l0)) << 10) + h;

    u16 b0[2][8], b1v[2][8], b2v[2][8], bx[2][8], bc[2][8];
    #define SLOAD(g0, s) { \
        _Pragma("unroll") \
        for (int j = 0; j < 8; ++j) { \
            size_t rr = (size_t)((g0) * 8 + j); \
            size_t uo = ub + rr * 3072; \
            b0[s][j] = Uc[uo]; b1v[s][j] = Uc[uo + 1024]; b2v[s][j] = Uc[uo + 2048]; \
            size_t go = gbase + (rr << 10); \
            bx[s][j] = xnblend[go]; bc[s][j] = cnnb[go]; \
        } }
    #define SCOMP(g0, s) { \
        _Pragma("unroll") \
        for (int j = 0; j < 8; ++j) { \
            size_t go = gbase + ((size_t)((g0) * 8 + j) << 10); \
            float u0 = b2f(b0[s][j]), u1 = b2f(b1v[s][j]), u2 = b2f(b2v[s][j]); \
            float xn = b2f(bx[s][j]), cv = b2f(bc[s][j]); \
            float f = 1.0f / (1.0f + __expf(-(u1 + c * vfv + bfv))); \
            float cn = f * (c - u0) + u0; \
            float r_ = 1.0f / (1.0f + __expf(-(u2 + c * vrv + brv))); \
            float e2 = __expf(-2.0f * fabsf(cn)); \
            float th = (1.0f - e2) / (1.0f + e2); \
            th = (cn < 0.0f) ? -th : th; \
            float xr = xn * SXC; \
            float hh = r_ * (th - xr) + xr; \
            xnblend[go] = f2b(lamv * (cv - hh) + hh); \
            c = cn; \
        } }

    SLOAD(0, 0);
    for (int g = 0; g < LC / 8; g += 2) {
        SLOAD(g + 1, 1);
        SCOMP(g, 0);
        if (g + 2 < LC / 8) SLOAD(g + 2, 0);
        SCOMP(g + 1, 1);
    }
    carry[(b << 10) + h] = c;
    #undef SLOAD
    #undef SCOMP
}

// ------------------------------------------------------------------
__global__ __launch_bounds__(256) void k_rms_ln1(const u16* __restrict__ blend, const void* __restrict__ x,
                                                 const float* __restrict__ P, const int* __restrict__ flag,
                                                 float* __restrict__ scale, u16* __restrict__ A1) {
    __shared__ float sred[8];
    int t = blockIdx.x, tid = threadIdx.x, fl = flag[0];
    ushort4 bv = ((const ushort4*)(blend + ((size_t)t << 10)))[tid];
    float b0 = b2f(bv.x), b1 = b2f(bv.y), b2 = b2f(bv.z), b3 = b2f(bv.w);
    float ss = b0 * b0 + b1 * b1 + b2 * b2 + b3 * b3, dummy = 0.0f;
    breduce2(ss, dummy, sred, sred + 4, tid);
    float sc = rsqrtf(ss * (1.0f / 1024.0f) + 1e-6f);
    if (tid == 0) scale[t] = sc;
    size_t gb = ((size_t)t << 10) + tid * 4;
    int c = tid * 4;
    float g0 = b0 * sc * P[P_RMS + c + 0] * ldp(x, gb + 0, fl);
    float g1 = b1 * sc * P[P_RMS + c + 1] * ldp(x, gb + 1, fl);
    float g2 = b2 * sc * P[P_RMS + c + 2] * ldp(x, gb + 2, fl);
    float g3 = b3 * sc * P[P_RMS + c + 3] * ldp(x, gb + 3, fl);
    float s2 = g0 + g1 + g2 + g3;
    float ss2 = g0 * g0 + g1 * g1 + g2 * g2 + g3 * g3;
    breduce2(s2, ss2, sred, sred + 4, tid);
    float m = s2 * (1.0f / 1024.0f);
    float var = ss2 * (1.0f / 1024.0f) - m * m;
    float rs = rsqrtf(var + 1e-5f);
    ushort4 o;
    o.x = f2b(gelu_exact((g0 - m) * rs * P[P_LN1W + c + 0] + P[P_LN1B + c + 0]));
    o.y = f2b(gelu_exact((g1 - m) * rs * P[P_LN1W + c + 1] + P[P_LN1B + c + 1]));
    o.z = f2b(gelu_exact((g2 - m) * rs * P[P_LN1W + c + 2] + P[P_LN1B + c + 2]));
    o.w = f2b(gelu_exact((g3 - m) * rs * P[P_LN1W + c + 3] + P[P_LN1B + c + 3]));
    ((ushort4*)(A1 + ((size_t)t << 10)))[tid] = o;
}

__global__ __launch_bounds__(256) void k_ln2_gelu(const u16* __restrict__ T1c, const float* __restrict__ P,
                                                  u16* __restrict__ A2c) {
    __shared__ float sred[8];
    int t = blockIdx.x, tid = threadIdx.x;
    const ushort4* tp = (const ushort4*)(T1c + ((size_t)t << 11));
    ushort4 va = tp[tid * 2], vb = tp[tid * 2 + 1];
    float e[8] = { b2f(va.x), b2f(va.y), b2f(va.z), b2f(va.w),
                   b2f(vb.x), b2f(vb.y), b2f(vb.z), b2f(vb.w) };
    float s = 0.0f, ss = 0.0f;
    #pragma unroll
    for (int i = 0; i < 8; ++i) { s += e[i]; ss += e[i] * e[i]; }
    breduce2(s, ss, sred, sred + 4, tid);
    float m = s * (1.0f / 2048.0f);
    float var = ss * (1.0f / 2048.0f) - m * m;
    float rs = rsqrtf(var + 1e-5f);
    int c = tid * 8;
    u16 oo[8];
    #pragma unroll
    for (int i = 0; i < 8; ++i)
        oo[i] = f2b(gelu_exact((e[i] - m) * rs * P[P_LN2W + c + i] + P[P_LN2B + c + i]));
    ushort4 oa, ob;
    oa.x = oo[0]; oa.y = oo[1]; oa.z = oo[2]; oa.w = oo[3];
    ob.x = oo[4]; ob.y = oo[5]; ob.z = oo[6]; ob.w = oo[7];
    ushort4* op = (ushort4*)(A2c + ((size_t)t << 11));
    op[tid * 2] = oa; op[tid * 2 + 1] = ob;
}

// ------------------------------------------------------------------
extern "C" void kernel_launch(void* const* d_in, const int* in_sizes, int n_in,
                              void* d_out, int out_size, void* d_ws, size_t ws_size,
                              hipStream_t stream) {
    (void)in_sizes; (void)n_in; (void)out_size;
    const void* x        = d_in[0];
    const void* conv_w   = d_in[1];
    const void* conv_b   = d_in[2];
    const void* sru_ln_w = d_in[3];
    const void* sru_ln_b = d_in[4];
    const void* sru_W    = d_in[5];
    const void* sru_vf   = d_in[6];
    const void* sru_vr   = d_in[7];
    const void* sru_bf   = d_in[8];
    const void* sru_br   = d_in[9];
    const void* lambda_w = d_in[10];
    const void* rms_w    = d_in[11];
    const void* ln1_w    = d_in[12];
    const void* ln1_b    = d_in[13];
    const void* lin1_w   = d_in[14];
    const void* ln2_w    = d_in[15];
    const void* ln2_b    = d_in[16];
    const void* lin2_w   = d_in[17];
    const void* lin2_b   = d_in[18];

    if (ws_size < WS_REQ) {
        float sv = 1000.0f + (float)(ws_size >> 20);
        k_fill<<<16384, 256, 0, stream>>>((float*)d_out, sv);
        return;
    }

    char* ws = (char*)d_ws;
    u16*   xb    = (u16*)(ws + OFF_XB);
    u16*   cnnb  = (u16*)(ws + OFF_CNNB);
    u16*   xnb   = (u16*)(ws + OFF_XNB);
    u16*   Uc    = (u16*)(ws + OFF_U4C);
    u16*   WcT   = (u16*)(ws + OFF_WCT);
    u16*   WsruT = (u16*)(ws + OFF_WSRUT);
    u16*   W1T   = (u16*)(ws + OFF_W1T);
    u16*   W2T   = (u16*)(ws + OFF_W2T);
    float* carry = (float*)(ws + OFF_CARRY);
    float* P     = (float*)(ws + OFF_P);
    float* scale = (float*)(ws + OFF_SCALE);
    int*   flag  = (int*)(ws + OFF_FLAG);
    float* zbuf  = (float*)(ws + OFF_ZERO);
    const u16* zb16 = (const u16*)zbuf;
    u16*   A1  = xb;                              // xb dead after conv GEMM
    u16*   T1c = cnnb;                            // cnnb dead after scan
    u16*   A2c = (u16*)(ws + OFF_CNNB + 33554432);

    k_detect<<<1, 256, 0, stream>>>((const u16*)x, flag);
    k_params<<<64, 256, 0, stream>>>(flag, conv_b, sru_ln_w, sru_ln_b, sru_vf, sru_vr,
                                     sru_bf, sru_br, lambda_w, rms_w, ln1_w, ln1_b,
                                     lin2_b, ln2_w, ln2_b, P, zbuf);
    k_x2b<<<32768, 256, 0, stream>>>(flag, x, xb);
    k_conv_reorder<<<1024, 256, 0, stream>>>(flag, conv_w, WcT);
    // conv: M=32768 N=1024 K=4096 -> 256x8 = 2048 tiles
    k_gemm<1, 1><<<2048, 256, 0, stream>>>(xb, WcT, 1024, 4096, 8, 0, 0,
                                           P, nullptr, nullptr, nullptr, flag, zb16, cnnb);
    k_ln<<<32768, 256, 0, stream>>>(cnnb, P, xnb);
    k_transpose<<<3072, 256, 0, stream>>>(flag, sru_W, WsruT, 1024, 3072);
    // U in L-chunks, alternating with scan; U chunk M=4096 N=3072 -> 32x24 = 768 tiles
    for (int ch = 0; ch < NCH; ++ch) {
        int l0 = ch * LC;
        k_gemm<2, 0><<<768, 256, 0, stream>>>(xnb, WsruT, 3072, 1024, 24, l0, 0,
                                              P, nullptr, nullptr, nullptr, flag, zb16, Uc);
        k_scan<<<dim3(4, 8), 256, 0, stream>>>(Uc, cnnb, xnb, carry, P, l0, ch == 0);
    }
    k_rms_ln1<<<32768, 256, 0, stream>>>(xnb, x, P, flag, scale, A1);
    k_transpose<<<2048, 256, 0, stream>>>(flag, lin1_w, W1T, 1024, 2048);
    k_transpose<<<1024, 256, 0, stream>>>(flag, lin2_w, W2T, 2048, 1024);
    // FFN in token chunks of 8192: GEMM1 64x16=1024 tiles, GEMM2 64x8=512 tiles
    for (int c = 0; c < NFC; ++c) {
        int tok0 = c * MC;
        k_gemm<0, 0><<<1024, 256, 0, stream>>>(A1 + ((size_t)tok0 << 10), W1T, 2048, 1024, 16, 0, 0,
                                               P, nullptr, nullptr, nullptr, flag, zb16, T1c);
        k_ln2_gelu<<<MC, 256, 0, stream>>>(T1c, P, A2c);
        k_gemm<0, 3><<<512, 256, 0, stream>>>(A2c, W2T, 1024, 2048, 8, 0, tok0,
                                              P, xnb, x, scale, flag, zb16, d_out);
    }
}

// Round 3
// 2827.475 us; speedup vs baseline: 1.8123x; 1.0658x over previous
//
#include <hip/hip_runtime.h>

typedef unsigned short u16;
typedef short bf16x8 __attribute__((ext_vector_type(8)));
typedef float f32x4 __attribute__((ext_vector_type(4)));
typedef unsigned short u16x8 __attribute__((ext_vector_type(8)));

#define NTOK 32768
#define LC 1024           // L-chunk for U/scan
#define L2LC 10
#define NCH 4             // 4096 / LC
#define MC 8192           // token chunk for FFN
#define NFC 4             // 32768 / MC

// workspace offsets (bytes)
#define OFF_XB     0ull              // 64 MiB  bf16 x -> Uc chunk (48M) -> A1
#define OFF_CNNB   67108864ull       // 64 MiB  cnn bf16 -> later T1c(32M)+A2c(32M)
#define OFF_XNB    134217728ull      // 64 MiB  xn bf16 -> blend (in place)
#define OFF_U4C    201326592ull      // 32 MiB  (unused this rev)
#define OFF_WCT    234881024ull      // 8 MiB
#define OFF_WSRUT  243269632ull      // 6 MiB
#define OFF_W1T    249561088ull      // 4 MiB
#define OFF_W2T    253755392ull      // 4 MiB
#define OFF_CARRY  257949696ull      // 32 KiB f32[8192]
#define OFF_P      257982464ull      // 64 KiB param block f32[16384]
#define OFF_SCALE  258048000ull      // 128 KiB f32[32768]
#define OFF_FLAG   258179072ull      // int
#define OFF_ZERO   258179328ull      // 128 B zero pad for im2col OOB lanes
#define WS_REQ     258183168ull

// param-block offsets (floats)
#define P_CONVB 0
#define P_LNW   1024
#define P_LNB   2048
#define P_VF    3072
#define P_VR    4096
#define P_BF    5120
#define P_BR    6144
#define P_LAM   7168
#define P_RMS   8192
#define P_LN1W  9216
#define P_LN1B  10240
#define P_LIN2B 11264
#define P_LN2W  12288
#define P_LN2B  14336

__device__ __forceinline__ float b2f(u16 u) {
    union { unsigned int i; float f; } v; v.i = ((unsigned int)u) << 16; return v.f;
}
__device__ __forceinline__ u16 f2b(float f) {
    union { float f; unsigned int i; } v; v.f = f;
    unsigned int r = v.i + 0x7fffu + ((v.i >> 16) & 1u);
    return (u16)(r >> 16);
}
__device__ __forceinline__ float ldp(const void* p, size_t i, int fl) {
    return fl ? ((const float*)p)[i] : b2f(((const u16*)p)[i]);
}
__device__ __forceinline__ float gelu_exact(float a) {
    return 0.5f * a * (1.0f + erff(a * 0.70710678118654752f));
}

// async global->LDS, 16B per lane; dest = wave-uniform base + lane*16
typedef const __attribute__((address_space(1))) void gas_void;
typedef __attribute__((address_space(3))) void las_void;
__device__ __forceinline__ void gl16(const u16* g, u16* l) {
    __builtin_amdgcn_global_load_lds((gas_void*)g, (las_void*)l, 16, 0, 0);
}

// k-group XOR swizzle: LDS[row][c] holds global k-group (c ^ f(row)).
__device__ __forceinline__ int kswz(int row) { return (row + (row >> 3)) & 3; }

// ------------------------------------------------------------------
__global__ __launch_bounds__(256) void k_fill(float* out, float v) {
    size_t i = ((size_t)blockIdx.x * 256 + threadIdx.x) * 4;
    float4 o; o.x = v; o.y = v; o.z = v; o.w = v;
    *(float4*)(out + i) = o;
}

// dtype detect: for f32 data the EVEN u16 of each pair is the low mantissa
// half -> random bits -> wild exponents/NaN when read as bf16.
__global__ void k_detect(const u16* __restrict__ x, int* __restrict__ flag) {
    __shared__ int cnt[4];
    int tid = threadIdx.x;
    int c = 0;
    for (int i = 0; i < 16; ++i) {
        float f = b2f(x[2 * (tid * 16 + i)]);
        if (f != f || fabsf(f) > 1e6f) c++;
    }
    #pragma unroll
    for (int m = 32; m; m >>= 1) c += __shfl_xor(c, m, 64);
    if ((tid & 63) == 0) cnt[tid >> 6] = c;
    __syncthreads();
    if (tid == 0) flag[0] = (cnt[0] + cnt[1] + cnt[2] + cnt[3] > 100) ? 1 : 0;
}

__global__ __launch_bounds__(256) void k_params(const int* __restrict__ flag,
        const void* conv_b, const void* lnw, const void* lnb,
        const void* vf, const void* vr, const void* bf, const void* br,
        const void* lam, const void* rms, const void* ln1w, const void* ln1b,
        const void* lin2b, const void* ln2w, const void* ln2b,
        float* __restrict__ P, float* __restrict__ Z) {
    if (blockIdx.x == 0 && threadIdx.x < 32) Z[threadIdx.x] = 0.0f;
    int idx = blockIdx.x * 256 + threadIdx.x;   // 0..16383
    int fl = flag[0];
    int vec = idx >> 10, off = idx & 1023;
    const void* src; size_t so = off;
    switch (vec) {
        case 0: src = conv_b; break;
        case 1: src = lnw; break;
        case 2: src = lnb; break;
        case 3: src = vf; break;
        case 4: src = vr; break;
        case 5: src = bf; break;
        case 6: src = br; break;
        case 7: src = lam; break;
        case 8: src = rms; break;
        case 9: src = ln1w; break;
        case 10: src = ln1b; break;
        case 11: src = lin2b; break;
        case 12: case 13: src = ln2w; so = idx - P_LN2W; break;
        default: src = ln2b; so = idx - P_LN2B; break;
    }
    P[idx] = ldp(src, so, fl);
}

__global__ __launch_bounds__(256) void k_x2b(const int* __restrict__ flag,
                                             const void* __restrict__ x, u16* __restrict__ xb) {
    size_t i = (size_t)blockIdx.x * 256 + threadIdx.x;
    int fl = flag[0];
    ushort4 o;
    if (fl) {
        float4 v = ((const float4*)x)[i];
        o.x = f2b(v.x); o.y = f2b(v.y); o.z = f2b(v.z); o.w = f2b(v.w);
    } else {
        o = ((const ushort4*)x)[i];
    }
    ((ushort4*)xb)[i] = o;
}

// conv_w (O,I,K=4) -> WcT[o][k*1024+i] bf16
__global__ __launch_bounds__(256) void k_conv_reorder(const int* __restrict__ flag,
                                                      const void* __restrict__ w, u16* __restrict__ out) {
    int o = blockIdx.x, fl = flag[0];
    for (int kk = threadIdx.x; kk < 4096; kk += 256) {
        int k = kk >> 10, i = kk & 1023;
        out[(size_t)o * 4096 + kk] = f2b(ldp(w, (size_t)o * 4096 + i * 4 + k, fl));
    }
}

__global__ __launch_bounds__(256) void k_transpose(const int* __restrict__ flag,
                                                   const void* __restrict__ in, u16* __restrict__ out,
                                                   int R, int C) {
    int n = blockIdx.x, fl = flag[0];
    for (int r = threadIdx.x; r < R; r += 256)
        out[(size_t)n * R + r] = f2b(ldp(in, (size_t)r * C + n, fl));
}

// ------------------------------------------------------------------
// GEMM C[M,N]=A[M,K]*Bt[N,K]^T, bf16 MFMA 16x16x32, 128x128 tile, BK=32.
// m97 structure: global_load_lds(16B) staging, k-group-XOR-swizzled LDS,
// 2 barriers/K-step, XCD-chunked bijective block swizzle.
// MODE 0: plain A rows. MODE 1: conv im2col (zero-pad taps via zb).
// MODE 2: chunked-U row remap token=((row>>L2LC)<<12)+l0+(row&(LC-1)).
// EPI 0: bf16 out. EPI 1: +conv_b bf16. EPI 2: grouped-U scatter
//   [b*3+p][r>>3][h][8] (8B ushort4 per lane). EPI 3: +lin2_b + gated residual.
template<int MODE, int EPI>
__global__ __launch_bounds__(256) void k_gemm(const u16* __restrict__ A, const u16* __restrict__ Bt,
                                              int N, int K, int nn, int l0, int tok0,
                                              const float* __restrict__ P,
                                              const u16* __restrict__ blend,
                                              const void* __restrict__ xorig,
                                              const float* __restrict__ scale,
                                              const int* __restrict__ flag,
                                              const u16* __restrict__ zb,
                                              void* __restrict__ outp) {
    __shared__ __align__(16) u16 As[128 * 32];
    __shared__ __align__(16) u16 Bs[128 * 32];
    const int tid = threadIdx.x;
    const int lane = tid & 63, wid = tid >> 6;
    const int wm = wid >> 1, wn = wid & 1;

    // XCD-chunked bijective swizzle (m204)
    const int nwg = gridDim.x, bid = blockIdx.x;
    const int q = nwg >> 3, r = nwg & 7;
    const int xcd = bid & 7, idx = bid >> 3;
    const int swz = idx + (xcd < r ? xcd * (q + 1) : r * (q + 1) + (xcd - r) * q);
    const int mi = swz / nn, ni = swz - mi * nn;
    const int m0 = mi << 7, n0 = ni << 7;

    // staging: s = tid+256j; dest byte s*16 = LDS[s>>2][(s&3)*16B];
    // source k-group pre-XORed so reads XOR the same pattern (rule #21).
    const u16* pa[2]; const u16* pb[2]; int kmin[2];
    u16 *la[2], *lb[2];
    #pragma unroll
    for (int j = 0; j < 2; ++j) {
        int s = tid + j * 256;
        int row = s >> 2;
        int kg = ((s & 3) ^ kswz(row)) << 3;
        la[j] = As + ((s & ~63) << 3);
        lb[j] = Bs + ((s & ~63) << 3);
        pb[j] = Bt + (size_t)(n0 + row) * K + kg;
        kmin[j] = 0;
        if (MODE == 1) {
            int t = m0 + row, b = t >> 12, l = t & 4095;
            pa[j] = A + (((size_t)(b << 12) + (size_t)(l - 3)) << 10) + kg;
            kmin[j] = (3 - l) << 10;            // k0 < kmin -> tap reads zero pad
        } else if (MODE == 2) {
            int rg = m0 + row;
            int token = ((rg >> L2LC) << 12) + l0 + (rg & (LC - 1));
            pa[j] = A + ((size_t)token << 10) + kg;
        } else {
            pa[j] = A + (size_t)(m0 + row) * K + kg;
        }
    }

    f32x4 acc[4][4];
    #pragma unroll
    for (int a = 0; a < 4; ++a)
        #pragma unroll
        for (int b = 0; b < 4; ++b)
            #pragma unroll
            for (int rr = 0; rr < 4; ++rr) acc[a][b][rr] = 0.0f;

    // fragment ds_read offsets (u16 units), XOR matching the staging swizzle
    int ra[4], rb[4];
    #pragma unroll
    for (int sm = 0; sm < 4; ++sm) {
        int rowa = wm * 64 + sm * 16 + (lane & 15);
        int rowb = wn * 64 + sm * 16 + (lane & 15);
        ra[sm] = (rowa << 5) + ((((lane >> 4) ^ kswz(rowa)) & 3) << 3);
        rb[sm] = (rowb << 5) + ((((lane >> 4) ^ kswz(rowb)) & 3) << 3);
    }

    const int nkb = K >> 5;
    for (int kb = 0; kb < nkb; ++kb) {
        const int k0 = kb << 5;
        __syncthreads();                         // prev iter's LDS reads done
        #pragma unroll
        for (int j = 0; j < 2; ++j) {
            const u16* ga = pa[j] + k0;
            if (MODE == 1) ga = (k0 < kmin[j]) ? zb : ga;
            gl16(ga, la[j]);
            gl16(pb[j] + k0, lb[j]);
        }
        __syncthreads();                         // barrier drains vmcnt -> tile ready

        bf16x8 af[4], bfr[4];
        #pragma unroll
        for (int sm = 0; sm < 4; ++sm) af[sm] = *(const bf16x8*)(As + ra[sm]);
        #pragma unroll
        for (int sn = 0; sn < 4; ++sn) bfr[sn] = *(const bf16x8*)(Bs + rb[sn]);
        #pragma unroll
        for (int sm = 0; sm < 4; ++sm)
            #pragma unroll
            for (int sn = 0; sn < 4; ++sn)
                acc[sm][sn] = __builtin_amdgcn_mfma_f32_16x16x32_bf16(af[sm], bfr[sn], acc[sm][sn], 0, 0, 0);
    }

    int fl = 0;
    if (EPI == 3) fl = flag[0];
    // C/D layout: col=lane&15, row=(lane>>4)*4+reg
    #pragma unroll
    for (int sm = 0; sm < 4; ++sm) {
        #pragma unroll
        for (int sn = 0; sn < 4; ++sn) {
            int rbase = m0 + wm * 64 + sm * 16 + ((lane >> 4) * 4);
            int col   = n0 + wn * 64 + sn * 16 + (lane & 15);
            if (EPI == 2) {
                // grouped-U scatter: all 4 regs contiguous within the r-group
                int bI = rbase >> L2LC, rloc = rbase & (LC - 1);
                int p = col >> 10, hh = col & 1023;
                size_t idx8 = ((((size_t)(bI * 3 + p) * (LC / 8)) + (rloc >> 3)) << 10) + hh;
                ushort4 o4;
                o4.x = f2b(acc[sm][sn][0]); o4.y = f2b(acc[sm][sn][1]);
                o4.z = f2b(acc[sm][sn][2]); o4.w = f2b(acc[sm][sn][3]);
                *(ushort4*)((u16*)outp + (idx8 << 3) + (rloc & 7)) = o4;
            } else {
                #pragma unroll
                for (int rr = 0; rr < 4; ++rr) {
                    int rowg = rbase + rr;
                    float v = acc[sm][sn][rr];
                    if (EPI == 0) {
                        ((u16*)outp)[(size_t)rowg * N + col] = f2b(v);
                    } else if (EPI == 1) {
                        ((u16*)outp)[(size_t)rowg * N + col] = f2b(v + P[P_CONVB + col]);
                    } else {
                        size_t gi = ((size_t)(tok0 + rowg) << 10) + col;
                        float xv = ldp(xorig, gi, fl);
                        float g = b2f(blend[gi]) * scale[tok0 + rowg] * P[P_RMS + col] * xv;
                        float o = v + P[P_LIN2B + col] + g;
                        if (fl) ((float*)outp)[gi] = o;
                        else    ((u16*)outp)[gi] = f2b(o);
                    }
                }
            }
        }
    }
}

// ------------------------------------------------------------------
__device__ __forceinline__ void breduce2(float& a, float& b, volatile float* sa, volatile float* sb, int tid) {
    #pragma unroll
    for (int m = 32; m; m >>= 1) { a += __shfl_xor(a, m, 64); b += __shfl_xor(b, m, 64); }
    int lane = tid & 63, wid = tid >> 6;
    if (lane == 0) { sa[wid] = a; sb[wid] = b; }
    __syncthreads();
    a = sa[0] + sa[1] + sa[2] + sa[3];
    b = sb[0] + sb[1] + sb[2] + sb[3];
    __syncthreads();
}

__global__ __launch_bounds__(256) void k_ln(const u16* __restrict__ cnnb, const float* __restrict__ P,
                                            u16* __restrict__ xnb) {
    __shared__ float sred[8];
    int t = blockIdx.x, tid = threadIdx.x;
    ushort4 cv = ((const ushort4*)(cnnb + ((size_t)t << 10)))[tid];
    float v0 = b2f(cv.x), v1 = b2f(cv.y), v2 = b2f(cv.z), v3 = b2f(cv.w);
    float s = v0 + v1 + v2 + v3;
    float ss = v0 * v0 + v1 * v1 + v2 * v2 + v3 * v3;
    breduce2(s, ss, sred, sred + 4, tid);
    float m = s * (1.0f / 1024.0f);
    float var = ss * (1.0f / 1024.0f) - m * m;
    float rs = rsqrtf(var + 1e-5f);
    int c = tid * 4;
    ushort4 o;
    o.x = f2b((v0 - m) * rs * P[P_LNW + c + 0] + P[P_LNB + c + 0]);
    o.y = f2b((v1 - m) * rs * P[P_LNW + c + 1] + P[P_LNB + c + 1]);
    o.z = f2b((v2 - m) * rs * P[P_LNW + c + 2] + P[P_LNB + c + 2]);
    o.w = f2b((v3 - m) * rs * P[P_LNW + c + 3] + P[P_LNB + c + 3]);
    ((ushort4*)(xnb + ((size_t)t << 10)))[tid] = o;
}

// ------------------------------------------------------------------
// SRU scan; Uc grouped layout: plane p of batch b, L-group g, channel h:
// ushort8 at index ((b*3+p)*(LC/8)+g)*1024 + h. 128 single-wave blocks,
// triple-buffered prefetch (2 groups in flight).
__global__ __launch_bounds__(64) void k_scan(const u16* __restrict__ Uc, const u16* __restrict__ cnnb,
                                             u16* xnblend, float* __restrict__ carry,
                                             const float* __restrict__ P, int l0, int first) {
    int h = blockIdx.x * 64 + threadIdx.x;    // 0..1023
    int b = blockIdx.y;
    float vfv = P[P_VF + h], vrv = P[P_VR + h], bfv = P[P_BF + h], brv = P[P_BR + h], lamv = P[P_LAM + h];
    const float SXC = 1.00911627f;            // sqrt(1+exp(-4))
    float c = first ? 0.0f : carry[(b << 10) + h];
    const u16x8* U8 = (const u16x8*)Uc;
    size_t u0b = (((size_t)(b * 3 + 0) * (LC / 8)) << 10) + h;
    size_t u1b = (((size_t)(b * 3 + 1) * (LC / 8)) << 10) + h;
    size_t u2b = (((size_t)(b * 3 + 2) * (LC / 8)) << 10) + h;
    size_t gbase = (((size_t)(b * 4096 + l0)) << 10) + h;

    u16x8 a0[3], a1[3], a2[3];
    u16 bx[3][8], bc[3][8];
    #define SLOAD(g0, s) { \
        size_t gg = (size_t)(g0); \
        a0[s] = U8[u0b + (gg << 10)]; \
        a1[s] = U8[u1b + (gg << 10)]; \
        a2[s] = U8[u2b + (gg << 10)]; \
        _Pragma("unroll") \
        for (int j = 0; j < 8; ++j) { \
            size_t go = gbase + ((gg * 8 + j) << 10); \
            bx[s][j] = xnblend[go]; bc[s][j] = cnnb[go]; \
        } }
    #define SCOMP(g0, s) { \
        _Pragma("unroll") \
        for (int j = 0; j < 8; ++j) { \
            size_t go = gbase + (((size_t)(g0) * 8 + j) << 10); \
            float u0 = b2f(a0[s][j]), u1 = b2f(a1[s][j]), u2 = b2f(a2[s][j]); \
            float xn = b2f(bx[s][j]), cv = b2f(bc[s][j]); \
            float f = 1.0f / (1.0f + __expf(-(u1 + c * vfv + bfv))); \
            float cn = f * (c - u0) + u0; \
            float r_ = 1.0f / (1.0f + __expf(-(u2 + c * vrv + brv))); \
            float e2 = __expf(-2.0f * fabsf(cn)); \
            float th = (1.0f - e2) / (1.0f + e2); \
            th = (cn < 0.0f) ? -th : th; \
            float xr = xn * SXC; \
            float hh = r_ * (th - xr) + xr; \
            xnblend[go] = f2b(lamv * (cv - hh) + hh); \
            c = cn; \
        } }

    const int G = LC / 8;                     // 128 groups
    SLOAD(0, 0);
    SLOAD(1, 1);
    #pragma unroll 1
    for (int g = 0; g < G; g += 3) {
        if (g + 2 < G) SLOAD(g + 2, 2);
        SCOMP(g, 0);
        if (g + 3 < G) SLOAD(g + 3, 0);
        if (g + 1 < G) SCOMP(g + 1, 1);
        if (g + 4 < G) SLOAD(g + 4, 1);
        if (g + 2 < G) SCOMP(g + 2, 2);
    }
    carry[(b << 10) + h] = c;
    #undef SLOAD
    #undef SCOMP
}

// ------------------------------------------------------------------
__global__ __launch_bounds__(256) void k_rms_ln1(const u16* __restrict__ blend, const void* __restrict__ x,
                                                 const float* __restrict__ P, const int* __restrict__ flag,
                                                 float* __restrict__ scale, u16* __restrict__ A1) {
    __shared__ float sred[8];
    int t = blockIdx.x, tid = threadIdx.x, fl = flag[0];
    ushort4 bv = ((const ushort4*)(blend + ((size_t)t << 10)))[tid];
    float b0 = b2f(bv.x), b1 = b2f(bv.y), b2 = b2f(bv.z), b3 = b2f(bv.w);
    float ss = b0 * b0 + b1 * b1 + b2 * b2 + b3 * b3, dummy = 0.0f;
    breduce2(ss, dummy, sred, sred + 4, tid);
    float sc = rsqrtf(ss * (1.0f / 1024.0f) + 1e-6f);
    if (tid == 0) scale[t] = sc;
    size_t gb = ((size_t)t << 10) + tid * 4;
    int c = tid * 4;
    float g0 = b0 * sc * P[P_RMS + c + 0] * ldp(x, gb + 0, fl);
    float g1 = b1 * sc * P[P_RMS + c + 1] * ldp(x, gb + 1, fl);
    float g2 = b2 * sc * P[P_RMS + c + 2] * ldp(x, gb + 2, fl);
    float g3 = b3 * sc * P[P_RMS + c + 3] * ldp(x, gb + 3, fl);
    float s2 = g0 + g1 + g2 + g3;
    float ss2 = g0 * g0 + g1 * g1 + g2 * g2 + g3 * g3;
    breduce2(s2, ss2, sred, sred + 4, tid);
    float m = s2 * (1.0f / 1024.0f);
    float var = ss2 * (1.0f / 1024.0f) - m * m;
    float rs = rsqrtf(var + 1e-5f);
    ushort4 o;
    o.x = f2b(gelu_exact((g0 - m) * rs * P[P_LN1W + c + 0] + P[P_LN1B + c + 0]));
    o.y = f2b(gelu_exact((g1 - m) * rs * P[P_LN1W + c + 1] + P[P_LN1B + c + 1]));
    o.z = f2b(gelu_exact((g2 - m) * rs * P[P_LN1W + c + 2] + P[P_LN1B + c + 2]));
    o.w = f2b(gelu_exact((g3 - m) * rs * P[P_LN1W + c + 3] + P[P_LN1B + c + 3]));
    ((ushort4*)(A1 + ((size_t)t << 10)))[tid] = o;
}

__global__ __launch_bounds__(256) void k_ln2_gelu(const u16* __restrict__ T1c, const float* __restrict__ P,
                                                  u16* __restrict__ A2c) {
    __shared__ float sred[8];
    int t = blockIdx.x, tid = threadIdx.x;
    const ushort4* tp = (const ushort4*)(T1c + ((size_t)t << 11));
    ushort4 va = tp[tid * 2], vb = tp[tid * 2 + 1];
    float e[8] = { b2f(va.x), b2f(va.y), b2f(va.z), b2f(va.w),
                   b2f(vb.x), b2f(vb.y), b2f(vb.z), b2f(vb.w) };
    float s = 0.0f, ss = 0.0f;
    #pragma unroll
    for (int i = 0; i < 8; ++i) { s += e[i]; ss += e[i] * e[i]; }
    breduce2(s, ss, sred, sred + 4, tid);
    float m = s * (1.0f / 2048.0f);
    float var = ss * (1.0f / 2048.0f) - m * m;
    float rs = rsqrtf(var + 1e-5f);
    int c = tid * 8;
    u16 oo[8];
    #pragma unroll
    for (int i = 0; i < 8; ++i)
        oo[i] = f2b(gelu_exact((e[i] - m) * rs * P[P_LN2W + c + i] + P[P_LN2B + c + i]));
    ushort4 oa, ob;
    oa.x = oo[0]; oa.y = oo[1]; oa.z = oo[2]; oa.w = oo[3];
    ob.x = oo[4]; ob.y = oo[5]; ob.z = oo[6]; ob.w = oo[7];
    ushort4* op = (ushort4*)(A2c + ((size_t)t << 11));
    op[tid * 2] = oa; op[tid * 2 + 1] = ob;
}

// ------------------------------------------------------------------
extern "C" void kernel_launch(void* const* d_in, const int* in_sizes, int n_in,
                              void* d_out, int out_size, void* d_ws, size_t ws_size,
                              hipStream_t stream) {
    (void)in_sizes; (void)n_in; (void)out_size;
    const void* x        = d_in[0];
    const void* conv_w   = d_in[1];
    const void* conv_b   = d_in[2];
    const void* sru_ln_w = d_in[3];
    const void* sru_ln_b = d_in[4];
    const void* sru_W    = d_in[5];
    const void* sru_vf   = d_in[6];
    const void* sru_vr   = d_in[7];
    const void* sru_bf   = d_in[8];
    const void* sru_br   = d_in[9];
    const void* lambda_w = d_in[10];
    const void* rms_w    = d_in[11];
    const void* ln1_w    = d_in[12];
    const void* ln1_b    = d_in[13];
    const void* lin1_w   = d_in[14];
    const void* ln2_w    = d_in[15];
    const void* ln2_b    = d_in[16];
    const void* lin2_w   = d_in[17];
    const void* lin2_b   = d_in[18];

    if (ws_size < WS_REQ) {
        float sv = 1000.0f + (float)(ws_size >> 20);
        k_fill<<<16384, 256, 0, stream>>>((float*)d_out, sv);
        return;
    }

    char* ws = (char*)d_ws;
    u16*   xb    = (u16*)(ws + OFF_XB);
    u16*   cnnb  = (u16*)(ws + OFF_CNNB);
    u16*   xnb   = (u16*)(ws + OFF_XNB);
    u16*   Uc    = (u16*)(ws + OFF_XB);           // 48 MiB; xb dead after conv
    u16*   WcT   = (u16*)(ws + OFF_WCT);
    u16*   WsruT = (u16*)(ws + OFF_WSRUT);
    u16*   W1T   = (u16*)(ws + OFF_W1T);
    u16*   W2T   = (u16*)(ws + OFF_W2T);
    float* carry = (float*)(ws + OFF_CARRY);
    float* P     = (float*)(ws + OFF_P);
    float* scale = (float*)(ws + OFF_SCALE);
    int*   flag  = (int*)(ws + OFF_FLAG);
    float* zbuf  = (float*)(ws + OFF_ZERO);
    const u16* zb16 = (const u16*)zbuf;
    u16*   A1  = xb;                              // Uc dead after last scan
    u16*   T1c = cnnb;                            // cnnb dead after scan
    u16*   A2c = (u16*)(ws + OFF_CNNB + 33554432);

    k_detect<<<1, 256, 0, stream>>>((const u16*)x, flag);
    k_params<<<64, 256, 0, stream>>>(flag, conv_b, sru_ln_w, sru_ln_b, sru_vf, sru_vr,
                                     sru_bf, sru_br, lambda_w, rms_w, ln1_w, ln1_b,
                                     lin2_b, ln2_w, ln2_b, P, zbuf);
    k_x2b<<<32768, 256, 0, stream>>>(flag, x, xb);
    k_conv_reorder<<<1024, 256, 0, stream>>>(flag, conv_w, WcT);
    // conv: M=32768 N=1024 K=4096 -> 256x8 = 2048 tiles
    k_gemm<1, 1><<<2048, 256, 0, stream>>>(xb, WcT, 1024, 4096, 8, 0, 0,
                                           P, nullptr, nullptr, nullptr, flag, zb16, cnnb);
    k_ln<<<32768, 256, 0, stream>>>(cnnb, P, xnb);
    k_transpose<<<3072, 256, 0, stream>>>(flag, sru_W, WsruT, 1024, 3072);
    // U in L-chunks (LC=1024), alternating with scan; M=8192 N=3072 -> 64x24 = 1536 tiles
    for (int ch = 0; ch < NCH; ++ch) {
        int l0 = ch * LC;
        k_gemm<2, 2><<<1536, 256, 0, stream>>>(xnb, WsruT, 3072, 1024, 24, l0, 0,
                                               P, nullptr, nullptr, nullptr, flag, zb16, Uc);
        k_scan<<<dim3(16, 8), 64, 0, stream>>>(Uc, cnnb, xnb, carry, P, l0, ch == 0);
    }
    k_rms_ln1<<<32768, 256, 0, stream>>>(xnb, x, P, flag, scale, A1);
    k_transpose<<<2048, 256, 0, stream>>>(flag, lin1_w, W1T, 1024, 2048);
    k_transpose<<<1024, 256, 0, stream>>>(flag, lin2_w, W2T, 2048, 1024);
    // FFN in token chunks of 8192: GEMM1 64x16=1024 tiles, GEMM2 64x8=512 tiles
    for (int c = 0; c < NFC; ++c) {
        int tok0 = c * MC;
        k_gemm<0, 0><<<1024, 256, 0, stream>>>(A1 + ((size_t)tok0 << 10), W1T, 2048, 1024, 16, 0, 0,
                                               P, nullptr, nullptr, nullptr, flag, zb16, T1c);
        k_ln2_gelu<<<MC, 256, 0, stream>>>(T1c, P, A2c);
        k_gemm<0, 3><<<512, 256, 0, stream>>>(A2c, W2T, 1024, 2048, 8, 0, tok0,
                                              P, xnb, x, scale, flag, zb16, d_out);
    }
}

// Round 4
// 2640.867 us; speedup vs baseline: 1.9403x; 1.0707x over previous
//
#include <hip/hip_runtime.h>

typedef unsigned short u16;
typedef short bf16x8 __attribute__((ext_vector_type(8)));
typedef float f32x4 __attribute__((ext_vector_type(4)));
typedef unsigned short u16x8 __attribute__((ext_vector_type(8)));

#define LC 512            // L-chunk for U/scan
#define L2LC 9
#define LCG 64            // LC/8 groups
#define NCH 8             // 4096 / LC
#define MC 8192           // token chunk for FFN G1

// workspace offsets (bytes)
#define OFF_XB     0ull              // 64 MiB  bf16 x -> UcA(24M)+UcB(24M) -> A1
#define OFF_UCB    25165824ull       // Uc double buffer B
#define OFF_CNNB   67108864ull       // 64 MiB  cnn bf16 -> later A2 (64M)
#define OFF_XNB    134217728ull      // 64 MiB  xn bf16 -> blend (in place)
#define OFF_U4C    201326592ull      // 32 MiB  T1c
#define OFF_WCT    234881024ull      // 8 MiB
#define OFF_WSRUT  243269632ull      // 6 MiB
#define OFF_W1T    249561088ull      // 4 MiB
#define OFF_W2T    253755392ull      // 4 MiB
#define OFF_CARRY  257949696ull      // 32 KiB f32[8192]
#define OFF_P      257982464ull      // 64 KiB param block f32[16384]
#define OFF_SCALE  258048000ull      // 128 KiB f32[32768]
#define OFF_FLAG   258179072ull      // int
#define OFF_ZERO   258179328ull      // 128 B zero pad for im2col OOB lanes
#define WS_REQ     258183168ull

// param-block offsets (floats)
#define P_CONVB 0
#define P_LNW   1024
#define P_LNB   2048
#define P_VF    3072
#define P_VR    4096
#define P_BF    5120
#define P_BR    6144
#define P_LAM   7168
#define P_RMS   8192
#define P_LN1W  9216
#define P_LN1B  10240
#define P_LIN2B 11264
#define P_LN2W  12288
#define P_LN2B  14336

__device__ __forceinline__ float b2f(u16 u) {
    union { unsigned int i; float f; } v; v.i = ((unsigned int)u) << 16; return v.f;
}
__device__ __forceinline__ u16 f2b(float f) {
    union { float f; unsigned int i; } v; v.f = f;
    unsigned int r = v.i + 0x7fffu + ((v.i >> 16) & 1u);
    return (u16)(r >> 16);
}
__device__ __forceinline__ float ldp(const void* p, size_t i, int fl) {
    return fl ? ((const float*)p)[i] : b2f(((const u16*)p)[i]);
}
__device__ __forceinline__ float gelu_exact(float a) {
    return 0.5f * a * (1.0f + erff(a * 0.70710678118654752f));
}

// async global->LDS, 16B per lane; dest = wave-uniform base + lane*16
typedef const __attribute__((address_space(1))) void gas_void;
typedef __attribute__((address_space(3))) void las_void;
__device__ __forceinline__ void gl16(const u16* g, u16* l) {
    __builtin_amdgcn_global_load_lds((gas_void*)g, (las_void*)l, 16, 0, 0);
}

// k-group XOR swizzle: LDS[row][c] holds global k-group (c ^ f(row)).
__device__ __forceinline__ int kswz(int row) { return (row + (row >> 3)) & 3; }

// ------------------------------------------------------------------
__global__ __launch_bounds__(256) void k_fill(float* out, float v) {
    size_t i = ((size_t)blockIdx.x * 256 + threadIdx.x) * 4;
    float4 o; o.x = v; o.y = v; o.z = v; o.w = v;
    *(float4*)(out + i) = o;
}

// dtype detect: for f32 data the EVEN u16 of each pair is the low mantissa
// half -> random bits -> wild exponents/NaN when read as bf16.
__global__ void k_detect(const u16* __restrict__ x, int* __restrict__ flag) {
    __shared__ int cnt[4];
    int tid = threadIdx.x;
    int c = 0;
    for (int i = 0; i < 16; ++i) {
        float f = b2f(x[2 * (tid * 16 + i)]);
        if (f != f || fabsf(f) > 1e6f) c++;
    }
    #pragma unroll
    for (int m = 32; m; m >>= 1) c += __shfl_xor(c, m, 64);
    if ((tid & 63) == 0) cnt[tid >> 6] = c;
    __syncthreads();
    if (tid == 0) flag[0] = (cnt[0] + cnt[1] + cnt[2] + cnt[3] > 100) ? 1 : 0;
}

__global__ __launch_bounds__(256) void k_params(const int* __restrict__ flag,
        const void* conv_b, const void* lnw, const void* lnb,
        const void* vf, const void* vr, const void* bf, const void* br,
        const void* lam, const void* rms, const void* ln1w, const void* ln1b,
        const void* lin2b, const void* ln2w, const void* ln2b,
        float* __restrict__ P, float* __restrict__ Z) {
    if (blockIdx.x == 0 && threadIdx.x < 32) Z[threadIdx.x] = 0.0f;
    int idx = blockIdx.x * 256 + threadIdx.x;   // 0..16383
    int fl = flag[0];
    int vec = idx >> 10, off = idx & 1023;
    const void* src; size_t so = off;
    switch (vec) {
        case 0: src = conv_b; break;
        case 1: src = lnw; break;
        case 2: src = lnb; break;
        case 3: src = vf; break;
        case 4: src = vr; break;
        case 5: src = bf; break;
        case 6: src = br; break;
        case 7: src = lam; break;
        case 8: src = rms; break;
        case 9: src = ln1w; break;
        case 10: src = ln1b; break;
        case 11: src = lin2b; break;
        case 12: case 13: src = ln2w; so = idx - P_LN2W; break;
        default: src = ln2b; so = idx - P_LN2B; break;
    }
    P[idx] = ldp(src, so, fl);
}

__global__ __launch_bounds__(256) void k_x2b(const int* __restrict__ flag,
                                             const void* __restrict__ x, u16* __restrict__ xb) {
    size_t i = (size_t)blockIdx.x * 256 + threadIdx.x;
    int fl = flag[0];
    ushort4 o;
    if (fl) {
        float4 v = ((const float4*)x)[i];
        o.x = f2b(v.x); o.y = f2b(v.y); o.z = f2b(v.z); o.w = f2b(v.w);
    } else {
        o = ((const ushort4*)x)[i];
    }
    ((ushort4*)xb)[i] = o;
}

// conv_w (O,I,K=4) -> WcT[o][k*1024+i] bf16; coalesced 16B/8B reads per channel
__global__ __launch_bounds__(256) void k_conv_reorder(const int* __restrict__ flag,
                                                      const void* __restrict__ w, u16* __restrict__ out) {
    int o = blockIdx.x, fl = flag[0];
    for (int i = threadIdx.x; i < 1024; i += 256) {
        float f0, f1, f2, f3;
        if (fl) {
            float4 v = ((const float4*)w)[(size_t)o * 1024 + i];
            f0 = v.x; f1 = v.y; f2 = v.z; f3 = v.w;
        } else {
            ushort4 v = ((const ushort4*)w)[(size_t)o * 1024 + i];
            f0 = b2f(v.x); f1 = b2f(v.y); f2 = b2f(v.z); f3 = b2f(v.w);
        }
        size_t ob = (size_t)o * 4096 + i;
        out[ob]        = f2b(f0);
        out[ob + 1024] = f2b(f1);
        out[ob + 2048] = f2b(f2);
        out[ob + 3072] = f2b(f3);
    }
}

// LDS-tiled transpose+cast: in [R][C] -> out [C][R] bf16, 64x64 tiles.
// grid (C/64, R/64); coalesced on both sides; [64][65] pad kills conflicts.
__global__ __launch_bounds__(256) void k_transpose_t(const int* __restrict__ flag,
                                                     const void* __restrict__ in, u16* __restrict__ out,
                                                     int R, int C) {
    __shared__ float tile[64][65];
    int fl = flag[0];
    int c0 = blockIdx.x * 64, r0 = blockIdx.y * 64;
    int tx = threadIdx.x & 63, ty = threadIdx.x >> 6;
    #pragma unroll
    for (int i = 0; i < 16; ++i) {
        int row = i * 4 + ty;
        tile[row][tx] = ldp(in, (size_t)(r0 + row) * C + c0 + tx, fl);
    }
    __syncthreads();
    #pragma unroll
    for (int i = 0; i < 16; ++i) {
        int col = i * 4 + ty;
        out[(size_t)(c0 + col) * R + r0 + tx] = f2b(tile[tx][col]);
    }
}

// ------------------------------------------------------------------
// GEMM core C[M,N]=A[M,K]*Bt[N,K]^T, bf16 MFMA 16x16x32, 128x128 tile, BK=32.
// m97 structure: global_load_lds(16B) staging, k-group-XOR-swizzled LDS,
// 2 barriers/K-step, XCD-chunked bijective block swizzle (bid/nwg params).
// MODE 0: plain A rows. MODE 1: conv im2col (zero-pad taps via zb).
// MODE 2: chunked-U row remap token=((row>>L2LC)<<12)+l0+(row&(LC-1)).
// EPI 0: bf16 out. EPI 1: +conv_b bf16. EPI 2: grouped-U scatter
//   [b*3+p][r>>3][h][8]. EPI 3: +lin2_b + gated residual.
template<int MODE, int EPI>
__device__ __forceinline__ void gemm_core(int bid, int nwg,
        const u16* __restrict__ A, const u16* __restrict__ Bt,
        int N, int K, int nn, int l0, int tok0,
        const float* __restrict__ P, const u16* __restrict__ blend,
        const void* __restrict__ xorig, const float* __restrict__ scale,
        const int* __restrict__ flag, const u16* __restrict__ zb,
        void* __restrict__ outp) {
    __shared__ __align__(16) u16 As[128 * 32];
    __shared__ __align__(16) u16 Bs[128 * 32];
    const int tid = threadIdx.x;
    const int lane = tid & 63;
    const int wid = tid >> 6;
    const int wm = wid >> 1, wn = wid & 1;

    // XCD-chunked bijective swizzle (m204)
    const int q = nwg >> 3, r = nwg & 7;
    const int xcd = bid & 7, idx = bid >> 3;
    const int swz = idx + (xcd < r ? xcd * (q + 1) : r * (q + 1) + (xcd - r) * q);
    const int mi = swz / nn, ni = swz - mi * nn;
    const int m0 = mi << 7, n0 = ni << 7;

    const u16* pa[2]; const u16* pb[2]; int kmin[2];
    u16 *la[2], *lb[2];
    #pragma unroll
    for (int j = 0; j < 2; ++j) {
        int s = tid + j * 256;
        int row = s >> 2;
        int kg = ((s & 3) ^ kswz(row)) << 3;
        la[j] = As + ((s & ~63) << 3);
        lb[j] = Bs + ((s & ~63) << 3);
        pb[j] = Bt + (size_t)(n0 + row) * K + kg;
        kmin[j] = 0;
        if (MODE == 1) {
            int t = m0 + row, b = t >> 12, l = t & 4095;
            pa[j] = A + (((size_t)(b << 12) + (size_t)(l - 3)) << 10) + kg;
            kmin[j] = (3 - l) << 10;            // k0 < kmin -> tap reads zero pad
        } else if (MODE == 2) {
            int rg = m0 + row;
            int token = ((rg >> L2LC) << 12) + l0 + (rg & (LC - 1));
            pa[j] = A + ((size_t)token << 10) + kg;
        } else {
            pa[j] = A + (size_t)(m0 + row) * K + kg;
        }
    }

    f32x4 acc[4][4];
    #pragma unroll
    for (int a = 0; a < 4; ++a)
        #pragma unroll
        for (int b = 0; b < 4; ++b)
            #pragma unroll
            for (int rr = 0; rr < 4; ++rr) acc[a][b][rr] = 0.0f;

    int ra[4], rb[4];
    #pragma unroll
    for (int sm = 0; sm < 4; ++sm) {
        int rowa = wm * 64 + sm * 16 + (lane & 15);
        int rowb = wn * 64 + sm * 16 + (lane & 15);
        ra[sm] = (rowa << 5) + ((((lane >> 4) ^ kswz(rowa)) & 3) << 3);
        rb[sm] = (rowb << 5) + ((((lane >> 4) ^ kswz(rowb)) & 3) << 3);
    }

    const int nkb = K >> 5;
    for (int kb = 0; kb < nkb; ++kb) {
        const int k0 = kb << 5;
        __syncthreads();
        #pragma unroll
        for (int j = 0; j < 2; ++j) {
            const u16* ga = pa[j] + k0;
            if (MODE == 1) ga = (k0 < kmin[j]) ? zb : ga;
            gl16(ga, la[j]);
            gl16(pb[j] + k0, lb[j]);
        }
        __syncthreads();

        bf16x8 af[4], bfr[4];
        #pragma unroll
        for (int sm = 0; sm < 4; ++sm) af[sm] = *(const bf16x8*)(As + ra[sm]);
        #pragma unroll
        for (int sn = 0; sn < 4; ++sn) bfr[sn] = *(const bf16x8*)(Bs + rb[sn]);
        #pragma unroll
        for (int sm = 0; sm < 4; ++sm)
            #pragma unroll
            for (int sn = 0; sn < 4; ++sn)
                acc[sm][sn] = __builtin_amdgcn_mfma_f32_16x16x32_bf16(af[sm], bfr[sn], acc[sm][sn], 0, 0, 0);
    }

    int fl = 0;
    if (EPI == 3) fl = flag[0];
    // C/D layout: col=lane&15, row=(lane>>4)*4+reg
    #pragma unroll
    for (int sm = 0; sm < 4; ++sm) {
        #pragma unroll
        for (int sn = 0; sn < 4; ++sn) {
            int rbase = m0 + wm * 64 + sm * 16 + ((lane >> 4) * 4);
            int col   = n0 + wn * 64 + sn * 16 + (lane & 15);
            if (EPI == 2) {
                int bI = rbase >> L2LC, rloc = rbase & (LC - 1);
                int p = col >> 10, hh = col & 1023;
                size_t idx8 = ((((size_t)(bI * 3 + p) * LCG) + (rloc >> 3)) << 10) + hh;
                ushort4 o4;
                o4.x = f2b(acc[sm][sn][0]); o4.y = f2b(acc[sm][sn][1]);
                o4.z = f2b(acc[sm][sn][2]); o4.w = f2b(acc[sm][sn][3]);
                *(ushort4*)((u16*)outp + (idx8 << 3) + (rloc & 7)) = o4;
            } else {
                #pragma unroll
                for (int rr = 0; rr < 4; ++rr) {
                    int rowg = rbase + rr;
                    float v = acc[sm][sn][rr];
                    if (EPI == 0) {
                        ((u16*)outp)[(size_t)rowg * N + col] = f2b(v);
                    } else if (EPI == 1) {
                        ((u16*)outp)[(size_t)rowg * N + col] = f2b(v + P[P_CONVB + col]);
                    } else {
                        size_t gi = ((size_t)(tok0 + rowg) << 10) + col;
                        float xv = ldp(xorig, gi, fl);
                        float g = b2f(blend[gi]) * scale[tok0 + rowg] * P[P_RMS + col] * xv;
                        float o = v + P[P_LIN2B + col] + g;
                        if (fl) ((float*)outp)[gi] = o;
                        else    ((u16*)outp)[gi] = f2b(o);
                    }
                }
            }
        }
    }
}

template<int MODE, int EPI>
__global__ __launch_bounds__(256) void k_gemm(const u16* __restrict__ A, const u16* __restrict__ Bt,
                                              int N, int K, int nn, int l0, int tok0,
                                              const float* __restrict__ P,
                                              const u16* __restrict__ blend,
                                              const void* __restrict__ xorig,
                                              const float* __restrict__ scale,
                                              const int* __restrict__ flag,
                                              const u16* __restrict__ zb,
                                              void* __restrict__ outp) {
    gemm_core<MODE, EPI>(blockIdx.x, gridDim.x, A, Bt, N, K, nn, l0, tok0,
                         P, blend, xorig, scale, flag, zb, outp);
}

// ------------------------------------------------------------------
// SRU scan core; Uc grouped layout: ushort8 at ((b*3+p)*LCG+g)*1024 + h.
__device__ __forceinline__ void scan_core(int h, int b, const u16* __restrict__ Uc,
        const u16* __restrict__ cnnb, u16* xnblend, float* __restrict__ carry,
        const float* __restrict__ P, int l0, int first) {
    float vfv = P[P_VF + h], vrv = P[P_VR + h], bfv = P[P_BF + h], brv = P[P_BR + h], lamv = P[P_LAM + h];
    const float SXC = 1.00911627f;            // sqrt(1+exp(-4))
    float c = first ? 0.0f : carry[(b << 10) + h];
    const u16x8* U8 = (const u16x8*)Uc;
    size_t u0b = (((size_t)(b * 3 + 0) * LCG) << 10) + h;
    size_t u1b = (((size_t)(b * 3 + 1) * LCG) << 10) + h;
    size_t u2b = (((size_t)(b * 3 + 2) * LCG) << 10) + h;
    size_t gbase = (((size_t)(b * 4096 + l0)) << 10) + h;

    u16x8 a0[3], a1[3], a2[3];
    u16 bx[3][8], bc[3][8];
    #define SLOAD(g0, s) { \
        size_t gg = (size_t)(g0); \
        a0[s] = U8[u0b + (gg << 10)]; \
        a1[s] = U8[u1b + (gg << 10)]; \
        a2[s] = U8[u2b + (gg << 10)]; \
        _Pragma("unroll") \
        for (int j = 0; j < 8; ++j) { \
            size_t go = gbase + ((gg * 8 + j) << 10); \
            bx[s][j] = xnblend[go]; bc[s][j] = cnnb[go]; \
        } }
    #define SCOMP(g0, s) { \
        _Pragma("unroll") \
        for (int j = 0; j < 8; ++j) { \
            size_t go = gbase + (((size_t)(g0) * 8 + j) << 10); \
            float u0 = b2f(a0[s][j]), u1 = b2f(a1[s][j]), u2 = b2f(a2[s][j]); \
            float xn = b2f(bx[s][j]), cv = b2f(bc[s][j]); \
            float f = 1.0f / (1.0f + __expf(-(u1 + c * vfv + bfv))); \
            float cn = f * (c - u0) + u0; \
            float r_ = 1.0f / (1.0f + __expf(-(u2 + c * vrv + brv))); \
            float e2 = __expf(-2.0f * fabsf(cn)); \
            float th = (1.0f - e2) / (1.0f + e2); \
            th = (cn < 0.0f) ? -th : th; \
            float xr = xn * SXC; \
            float hh = r_ * (th - xr) + xr; \
            xnblend[go] = f2b(lamv * (cv - hh) + hh); \
            c = cn; \
        } }

    SLOAD(0, 0);
    SLOAD(1, 1);
    #pragma unroll 1
    for (int g = 0; g < LCG; g += 3) {
        if (g + 2 < LCG) SLOAD(g + 2, 2);
        SCOMP(g, 0);
        if (g + 3 < LCG) SLOAD(g + 3, 0);
        if (g + 1 < LCG) SCOMP(g + 1, 1);
        if (g + 4 < LCG) SLOAD(g + 4, 1);
        if (g + 2 < LCG) SCOMP(g + 2, 2);
    }
    carry[(b << 10) + h] = c;
    #undef SLOAD
    #undef SCOMP
}

__global__ __launch_bounds__(256) void k_scan(const u16* __restrict__ Uc, const u16* __restrict__ cnnb,
                                              u16* xnblend, float* __restrict__ carry,
                                              const float* __restrict__ P, int l0, int first) {
    scan_core(blockIdx.x * 256 + threadIdx.x, blockIdx.y, Uc, cnnb, xnblend, carry, P, l0, first);
}

// Fused: blocks [0,32) run scan(ch-1) on UcPrev; blocks [32,800) run the
// U GEMM(ch) into UcCur. Independent data; scan rides free in spare wave slots.
__global__ __launch_bounds__(256) void k_uscan(const u16* __restrict__ xnb, const u16* __restrict__ WsruT,
                                               int l0g, u16* __restrict__ UcCur,
                                               const u16* __restrict__ UcPrev, const u16* __restrict__ cnnb,
                                               float* __restrict__ carry, int l0s, int first,
                                               const float* __restrict__ P, const int* __restrict__ flag,
                                               const u16* __restrict__ zb) {
    if (blockIdx.x < 32) {
        int sb = blockIdx.x;
        scan_core((sb & 3) * 256 + threadIdx.x, sb >> 2, UcPrev, cnnb,
                  (u16*)xnb, carry, P, l0s, first);
    } else {
        gemm_core<2, 2>(blockIdx.x - 32, 768, xnb, WsruT, 3072, 1024, 24, l0g, 0,
                        P, nullptr, nullptr, nullptr, flag, zb, (void*)UcCur);
    }
}

// ------------------------------------------------------------------
__device__ __forceinline__ void breduce2(float& a, float& b, volatile float* sa, volatile float* sb, int tid) {
    #pragma unroll
    for (int m = 32; m; m >>= 1) { a += __shfl_xor(a, m, 64); b += __shfl_xor(b, m, 64); }
    int lane = tid & 63, wid = tid >> 6;
    if (lane == 0) { sa[wid] = a; sb[wid] = b; }
    __syncthreads();
    a = sa[0] + sa[1] + sa[2] + sa[3];
    b = sb[0] + sb[1] + sb[2] + sb[3];
    __syncthreads();
}

__global__ __launch_bounds__(256) void k_ln(const u16* __restrict__ cnnb, const float* __restrict__ P,
                                            u16* __restrict__ xnb) {
    __shared__ float sred[8];
    int t = blockIdx.x, tid = threadIdx.x;
    ushort4 cv = ((const ushort4*)(cnnb + ((size_t)t << 10)))[tid];
    float v0 = b2f(cv.x), v1 = b2f(cv.y), v2 = b2f(cv.z), v3 = b2f(cv.w);
    float s = v0 + v1 + v2 + v3;
    float ss = v0 * v0 + v1 * v1 + v2 * v2 + v3 * v3;
    breduce2(s, ss, sred, sred + 4, tid);
    float m = s * (1.0f / 1024.0f);
    float var = ss * (1.0f / 1024.0f) - m * m;
    float rs = rsqrtf(var + 1e-5f);
    int c = tid * 4;
    ushort4 o;
    o.x = f2b((v0 - m) * rs * P[P_LNW + c + 0] + P[P_LNB + c + 0]);
    o.y = f2b((v1 - m) * rs * P[P_LNW + c + 1] + P[P_LNB + c + 1]);
    o.z = f2b((v2 - m) * rs * P[P_LNW + c + 2] + P[P_LNB + c + 2]);
    o.w = f2b((v3 - m) * rs * P[P_LNW + c + 3] + P[P_LNB + c + 3]);
    ((ushort4*)(xnb + ((size_t)t << 10)))[tid] = o;
}

// ------------------------------------------------------------------
__global__ __launch_bounds__(256) void k_rms_ln1(const u16* __restrict__ blend, const void* __restrict__ x,
                                                 const float* __restrict__ P, const int* __restrict__ flag,
                                                 float* __restrict__ scale, u16* __restrict__ A1) {
    __shared__ float sred[8];
    int t = blockIdx.x, tid = threadIdx.x, fl = flag[0];
    ushort4 bv = ((const ushort4*)(blend + ((size_t)t << 10)))[tid];
    float b0 = b2f(bv.x), b1 = b2f(bv.y), b2 = b2f(bv.z), b3 = b2f(bv.w);
    float ss = b0 * b0 + b1 * b1 + b2 * b2 + b3 * b3, dummy = 0.0f;
    breduce2(ss, dummy, sred, sred + 4, tid);
    float sc = rsqrtf(ss * (1.0f / 1024.0f) + 1e-6f);
    if (tid == 0) scale[t] = sc;
    size_t gb = ((size_t)t << 10) + tid * 4;
    int c = tid * 4;
    float g0 = b0 * sc * P[P_RMS + c + 0] * ldp(x, gb + 0, fl);
    float g1 = b1 * sc * P[P_RMS + c + 1] * ldp(x, gb + 1, fl);
    float g2 = b2 * sc * P[P_RMS + c + 2] * ldp(x, gb + 2, fl);
    float g3 = b3 * sc * P[P_RMS + c + 3] * ldp(x, gb + 3, fl);
    float s2 = g0 + g1 + g2 + g3;
    float ss2 = g0 * g0 + g1 * g1 + g2 * g2 + g3 * g3;
    breduce2(s2, ss2, sred, sred + 4, tid);
    float m = s2 * (1.0f / 1024.0f);
    float var = ss2 * (1.0f / 1024.0f) - m * m;
    float rs = rsqrtf(var + 1e-5f);
    ushort4 o;
    o.x = f2b(gelu_exact((g0 - m) * rs * P[P_LN1W + c + 0] + P[P_LN1B + c + 0]));
    o.y = f2b(gelu_exact((g1 - m) * rs * P[P_LN1W + c + 1] + P[P_LN1B + c + 1]));
    o.z = f2b(gelu_exact((g2 - m) * rs * P[P_LN1W + c + 2] + P[P_LN1B + c + 2]));
    o.w = f2b(gelu_exact((g3 - m) * rs * P[P_LN1W + c + 3] + P[P_LN1B + c + 3]));
    ((ushort4*)(A1 + ((size_t)t << 10)))[tid] = o;
}

__global__ __launch_bounds__(256) void k_ln2_gelu(const u16* __restrict__ T1c, const float* __restrict__ P,
                                                  u16* __restrict__ A2c) {
    __shared__ float sred[8];
    int t = blockIdx.x, tid = threadIdx.x;
    const ushort4* tp = (const ushort4*)(T1c + ((size_t)t << 11));
    ushort4 va = tp[tid * 2], vb = tp[tid * 2 + 1];
    float e[8] = { b2f(va.x), b2f(va.y), b2f(va.z), b2f(va.w),
                   b2f(vb.x), b2f(vb.y), b2f(vb.z), b2f(vb.w) };
    float s = 0.0f, ss = 0.0f;
    #pragma unroll
    for (int i = 0; i < 8; ++i) { s += e[i]; ss += e[i] * e[i]; }
    breduce2(s, ss, sred, sred + 4, tid);
    float m = s * (1.0f / 2048.0f);
    float var = ss * (1.0f / 2048.0f) - m * m;
    float rs = rsqrtf(var + 1e-5f);
    int c = tid * 8;
    u16 oo[8];
    #pragma unroll
    for (int i = 0; i < 8; ++i)
        oo[i] = f2b(gelu_exact((e[i] - m) * rs * P[P_LN2W + c + i] + P[P_LN2B + c + i]));
    ushort4 oa, ob;
    oa.x = oo[0]; oa.y = oo[1]; oa.z = oo[2]; oa.w = oo[3];
    ob.x = oo[4]; ob.y = oo[5]; ob.z = oo[6]; ob.w = oo[7];
    ushort4* op = (ushort4*)(A2c + ((size_t)t << 11));
    op[tid * 2] = oa; op[tid * 2 + 1] = ob;
}

// ------------------------------------------------------------------
extern "C" void kernel_launch(void* const* d_in, const int* in_sizes, int n_in,
                              void* d_out, int out_size, void* d_ws, size_t ws_size,
                              hipStream_t stream) {
    (void)in_sizes; (void)n_in; (void)out_size;
    const void* x        = d_in[0];
    const void* conv_w   = d_in[1];
    const void* conv_b   = d_in[2];
    const void* sru_ln_w = d_in[3];
    const void* sru_ln_b = d_in[4];
    const void* sru_W    = d_in[5];
    const void* sru_vf   = d_in[6];
    const void* sru_vr   = d_in[7];
    const void* sru_bf   = d_in[8];
    const void* sru_br   = d_in[9];
    const void* lambda_w = d_in[10];
    const void* rms_w    = d_in[11];
    const void* ln1_w    = d_in[12];
    const void* ln1_b    = d_in[13];
    const void* lin1_w   = d_in[14];
    const void* ln2_w    = d_in[15];
    const void* ln2_b    = d_in[16];
    const void* lin2_w   = d_in[17];
    const void* lin2_b   = d_in[18];

    if (ws_size < WS_REQ) {
        float sv = 1000.0f + (float)(ws_size >> 20);
        k_fill<<<16384, 256, 0, stream>>>((float*)d_out, sv);
        return;
    }

    char* ws = (char*)d_ws;
    u16*   xb    = (u16*)(ws + OFF_XB);
    u16*   cnnb  = (u16*)(ws + OFF_CNNB);
    u16*   xnb   = (u16*)(ws + OFF_XNB);
    u16*   UcA   = (u16*)(ws + OFF_XB);           // 24 MiB; xb dead after conv
    u16*   UcB   = (u16*)(ws + OFF_UCB);          // 24 MiB
    u16*   WcT   = (u16*)(ws + OFF_WCT);
    u16*   WsruT = (u16*)(ws + OFF_WSRUT);
    u16*   W1T   = (u16*)(ws + OFF_W1T);
    u16*   W2T   = (u16*)(ws + OFF_W2T);
    float* carry = (float*)(ws + OFF_CARRY);
    float* P     = (float*)(ws + OFF_P);
    float* scale = (float*)(ws + OFF_SCALE);
    int*   flag  = (int*)(ws + OFF_FLAG);
    float* zbuf  = (float*)(ws + OFF_ZERO);
    const u16* zb16 = (const u16*)zbuf;
    u16*   A1  = xb;                              // Uc dead after last scan
    u16*   T1c = (u16*)(ws + OFF_U4C);            // 32 MiB
    u16*   A2  = cnnb;                            // 64 MiB (2 chunks of 8192 rows)

    k_detect<<<1, 256, 0, stream>>>((const u16*)x, flag);
    k_params<<<64, 256, 0, stream>>>(flag, conv_b, sru_ln_w, sru_ln_b, sru_vf, sru_vr,
                                     sru_bf, sru_br, lambda_w, rms_w, ln1_w, ln1_b,
                                     lin2_b, ln2_w, ln2_b, P, zbuf);
    k_x2b<<<32768, 256, 0, stream>>>(flag, x, xb);
    k_conv_reorder<<<1024, 256, 0, stream>>>(flag, conv_w, WcT);
    // conv: M=32768 N=1024 K=4096 -> 256x8 = 2048 tiles
    k_gemm<1, 1><<<2048, 256, 0, stream>>>(xb, WcT, 1024, 4096, 8, 0, 0,
                                           P, nullptr, nullptr, nullptr, flag, zb16, cnnb);
    k_ln<<<32768, 256, 0, stream>>>(cnnb, P, xnb);
    k_transpose_t<<<dim3(48, 16), 256, 0, stream>>>(flag, sru_W, WsruT, 1024, 3072);
    // U chunks (LC=512) fused with previous chunk's scan
    k_gemm<2, 2><<<768, 256, 0, stream>>>(xnb, WsruT, 3072, 1024, 24, 0, 0,
                                          P, nullptr, nullptr, nullptr, flag, zb16, UcA);
    for (int ch = 1; ch < NCH; ++ch) {
        u16* cur  = (ch & 1) ? UcB : UcA;
        u16* prev = (ch & 1) ? UcA : UcB;
        k_uscan<<<800, 256, 0, stream>>>(xnb, WsruT, ch * LC, cur, prev, cnnb,
                                         carry, (ch - 1) * LC, ch == 1, P, flag, zb16);
    }
    k_scan<<<dim3(4, 8), 256, 0, stream>>>(UcB, cnnb, xnb, carry, P, (NCH - 1) * LC, 0);
    k_rms_ln1<<<32768, 256, 0, stream>>>(xnb, x, P, flag, scale, A1);
    k_transpose_t<<<dim3(32, 16), 256, 0, stream>>>(flag, lin1_w, W1T, 1024, 2048);
    k_transpose_t<<<dim3(16, 32), 256, 0, stream>>>(flag, lin2_w, W2T, 2048, 1024);
    // FFN: G1+ln2 per 8192-token chunk; G2 merged over 16384 tokens (full occupancy)
    for (int p = 0; p < 2; ++p) {
        int base = p * 16384;
        for (int h = 0; h < 2; ++h) {
            int tok0 = base + h * MC;
            k_gemm<0, 0><<<1024, 256, 0, stream>>>(A1 + ((size_t)tok0 << 10), W1T, 2048, 1024, 16, 0, 0,
                                                   P, nullptr, nullptr, nullptr, flag, zb16, T1c);
            k_ln2_gelu<<<MC, 256, 0, stream>>>(T1c, P, A2 + ((size_t)(h * MC) << 11));
        }
        // G2: M=16384 N=1024 K=2048 -> 128x8 = 1024 tiles
        k_gemm<0, 3><<<1024, 256, 0, stream>>>(A2, W2T, 1024, 2048, 8, 0, base,
                                               P, xnb, x, scale, flag, zb16, d_out);
    }
}

// Round 5
// 2546.196 us; speedup vs baseline: 2.0125x; 1.0372x over previous
//
#include <hip/hip_runtime.h>

typedef unsigned short u16;
typedef short bf16x8 __attribute__((ext_vector_type(8)));
typedef float f32x4 __attribute__((ext_vector_type(4)));
typedef unsigned short u16x8 __attribute__((ext_vector_type(8)));

#define LC 512            // L-chunk for U/scan
#define L2LC 9
#define LCG 64            // LC/8 groups
#define NCH 8             // 4096 / LC
#define MC 8192           // token chunk for FFN G1

// workspace offsets (bytes)
#define OFF_XB     0ull              // 64 MiB  bf16 x -> UcA(24M)+UcB(24M) -> A1
#define OFF_UCB    25165824ull       // Uc double buffer B
#define OFF_CNNB   67108864ull       // 64 MiB  cnn bf16 -> later A2 (64M)
#define OFF_XNB    134217728ull      // 64 MiB  xn bf16 -> blend (in place)
#define OFF_U4C    201326592ull      // 32 MiB  T1c
#define OFF_WCT    234881024ull      // 8 MiB
#define OFF_WSRUT  243269632ull      // 6 MiB
#define OFF_W1T    249561088ull      // 4 MiB
#define OFF_W2T    253755392ull      // 4 MiB
#define OFF_CARRY  257949696ull      // 32 KiB f32[8192]
#define OFF_P      257982464ull      // 64 KiB param block f32[16384]
#define OFF_SCALE  258048000ull      // 128 KiB f32[32768]
#define OFF_FLAG   258179072ull      // int
#define OFF_ZERO   258179328ull      // 128 B zero pad for im2col OOB lanes
#define WS_REQ     258183168ull

// param-block offsets (floats)
#define P_CONVB 0
#define P_LNW   1024
#define P_LNB   2048
#define P_VF    3072
#define P_VR    4096
#define P_BF    5120
#define P_BR    6144
#define P_LAM   7168
#define P_RMS   8192
#define P_LN1W  9216
#define P_LN1B  10240
#define P_LIN2B 11264
#define P_LN2W  12288
#define P_LN2B  14336

__device__ __forceinline__ float b2f(u16 u) {
    union { unsigned int i; float f; } v; v.i = ((unsigned int)u) << 16; return v.f;
}
__device__ __forceinline__ u16 f2b(float f) {
    union { float f; unsigned int i; } v; v.f = f;
    unsigned int r = v.i + 0x7fffu + ((v.i >> 16) & 1u);
    return (u16)(r >> 16);
}
__device__ __forceinline__ float ldp(const void* p, size_t i, int fl) {
    return fl ? ((const float*)p)[i] : b2f(((const u16*)p)[i]);
}
__device__ __forceinline__ float gelu_exact(float a) {
    return 0.5f * a * (1.0f + erff(a * 0.70710678118654752f));
}

// async global->LDS, 16B per lane; dest = wave-uniform base + lane*16
typedef const __attribute__((address_space(1))) void gas_void;
typedef __attribute__((address_space(3))) void las_void;
__device__ __forceinline__ void gl16(const u16* g, u16* l) {
    __builtin_amdgcn_global_load_lds((gas_void*)g, (las_void*)l, 16, 0, 0);
}

// 8-slot XOR swizzle over [128][64] u16 rows (8 x 16B slots per row):
// slot' = slot ^ swz8(row). 16-lane column reads spread across all 8 slots
// -> 2 lanes/bank-group = conflict-free (m136). Applied on BOTH the staging
// source (pre-XOR of per-lane global k-offset) and the frag ds_read (rule 21).
__device__ __forceinline__ int swz8(int row) { return (row + (row >> 3)) & 7; }

// ------------------------------------------------------------------
__global__ __launch_bounds__(256) void k_fill(float* out, float v) {
    size_t i = ((size_t)blockIdx.x * 256 + threadIdx.x) * 4;
    float4 o; o.x = v; o.y = v; o.z = v; o.w = v;
    *(float4*)(out + i) = o;
}

// dtype detect: for f32 data the EVEN u16 of each pair is the low mantissa
// half -> random bits -> wild exponents/NaN when read as bf16.
__global__ void k_detect(const u16* __restrict__ x, int* __restrict__ flag) {
    __shared__ int cnt[4];
    int tid = threadIdx.x;
    int c = 0;
    for (int i = 0; i < 16; ++i) {
        float f = b2f(x[2 * (tid * 16 + i)]);
        if (f != f || fabsf(f) > 1e6f) c++;
    }
    #pragma unroll
    for (int m = 32; m; m >>= 1) c += __shfl_xor(c, m, 64);
    if ((tid & 63) == 0) cnt[tid >> 6] = c;
    __syncthreads();
    if (tid == 0) flag[0] = (cnt[0] + cnt[1] + cnt[2] + cnt[3] > 100) ? 1 : 0;
}

__global__ __launch_bounds__(256) void k_params(const int* __restrict__ flag,
        const void* conv_b, const void* lnw, const void* lnb,
        const void* vf, const void* vr, const void* bf, const void* br,
        const void* lam, const void* rms, const void* ln1w, const void* ln1b,
        const void* lin2b, const void* ln2w, const void* ln2b,
        float* __restrict__ P, float* __restrict__ Z) {
    if (blockIdx.x == 0 && threadIdx.x < 32) Z[threadIdx.x] = 0.0f;
    int idx = blockIdx.x * 256 + threadIdx.x;   // 0..16383
    int fl = flag[0];
    int vec = idx >> 10, off = idx & 1023;
    const void* src; size_t so = off;
    switch (vec) {
        case 0: src = conv_b; break;
        case 1: src = lnw; break;
        case 2: src = lnb; break;
        case 3: src = vf; break;
        case 4: src = vr; break;
        case 5: src = bf; break;
        case 6: src = br; break;
        case 7: src = lam; break;
        case 8: src = rms; break;
        case 9: src = ln1w; break;
        case 10: src = ln1b; break;
        case 11: src = lin2b; break;
        case 12: case 13: src = ln2w; so = idx - P_LN2W; break;
        default: src = ln2b; so = idx - P_LN2B; break;
    }
    P[idx] = ldp(src, so, fl);
}

__global__ __launch_bounds__(256) void k_x2b(const int* __restrict__ flag,
                                             const void* __restrict__ x, u16* __restrict__ xb) {
    size_t i = (size_t)blockIdx.x * 256 + threadIdx.x;
    int fl = flag[0];
    ushort4 o;
    if (fl) {
        float4 v = ((const float4*)x)[i];
        o.x = f2b(v.x); o.y = f2b(v.y); o.z = f2b(v.z); o.w = f2b(v.w);
    } else {
        o = ((const ushort4*)x)[i];
    }
    ((ushort4*)xb)[i] = o;
}

// conv_w (O,I,K=4) -> WcT[o][k*1024+i] bf16; coalesced 16B/8B reads per channel
__global__ __launch_bounds__(256) void k_conv_reorder(const int* __restrict__ flag,
                                                      const void* __restrict__ w, u16* __restrict__ out) {
    int o = blockIdx.x, fl = flag[0];
    for (int i = threadIdx.x; i < 1024; i += 256) {
        float f0, f1, f2, f3;
        if (fl) {
            float4 v = ((const float4*)w)[(size_t)o * 1024 + i];
            f0 = v.x; f1 = v.y; f2 = v.z; f3 = v.w;
        } else {
            ushort4 v = ((const ushort4*)w)[(size_t)o * 1024 + i];
            f0 = b2f(v.x); f1 = b2f(v.y); f2 = b2f(v.z); f3 = b2f(v.w);
        }
        size_t ob = (size_t)o * 4096 + i;
        out[ob]        = f2b(f0);
        out[ob + 1024] = f2b(f1);
        out[ob + 2048] = f2b(f2);
        out[ob + 3072] = f2b(f3);
    }
}

// LDS-tiled transpose+cast: in [R][C] -> out [C][R] bf16, 64x64 tiles.
__global__ __launch_bounds__(256) void k_transpose_t(const int* __restrict__ flag,
                                                     const void* __restrict__ in, u16* __restrict__ out,
                                                     int R, int C) {
    __shared__ float tile[64][65];
    int fl = flag[0];
    int c0 = blockIdx.x * 64, r0 = blockIdx.y * 64;
    int tx = threadIdx.x & 63, ty = threadIdx.x >> 6;
    #pragma unroll
    for (int i = 0; i < 16; ++i) {
        int row = i * 4 + ty;
        tile[row][tx] = ldp(in, (size_t)(r0 + row) * C + c0 + tx, fl);
    }
    __syncthreads();
    #pragma unroll
    for (int i = 0; i < 16; ++i) {
        int col = i * 4 + ty;
        out[(size_t)(c0 + col) * R + r0 + tx] = f2b(tile[tx][col]);
    }
}

// ------------------------------------------------------------------
// GEMM core C[M,N]=A[M,K]*Bt[N,K]^T, bf16 MFMA 16x16x32, 128x128 tile, BK=64.
// m97 structure: global_load_lds(16B) staging, 8-slot-XOR-swizzled LDS,
// 2 barriers per 64-K step (half the drains of BK=32).
// n-MAJOR XCD chunking: each XCD owns whole n-panels -> B-panel L2-resident;
// A m-panels stream once per XCD and are L3-absorbed across XCDs.
// MODE 0: plain A rows. MODE 1: conv im2col (zero-pad taps via zb).
// MODE 2: chunked-U row remap token=((row>>L2LC)<<12)+l0+(row&(LC-1)).
// EPI 0: bf16 out. EPI 1: +conv_b bf16. EPI 2: grouped-U scatter
//   [b*3+p][r>>3][h][8]. EPI 3: +lin2_b + gated residual.
template<int MODE, int EPI>
__device__ __forceinline__ void gemm_core(int bid, int nwg,
        const u16* __restrict__ A, const u16* __restrict__ Bt,
        int N, int K, int nm, int l0, int tok0,
        const float* __restrict__ P, const u16* __restrict__ blend,
        const void* __restrict__ xorig, const float* __restrict__ scale,
        const int* __restrict__ flag, const u16* __restrict__ zb,
        void* __restrict__ outp) {
    __shared__ __align__(16) u16 As[128 * 64];
    __shared__ __align__(16) u16 Bs[128 * 64];
    const int tid = threadIdx.x;
    const int lane = tid & 63;
    const int wid = tid >> 6;
    const int wm = wid >> 1, wn = wid & 1;

    // XCD-chunked bijective swizzle (m204), n-major decode
    const int q = nwg >> 3, r = nwg & 7;
    const int xcd = bid & 7, idx = bid >> 3;
    const int swz = idx + (xcd < r ? xcd * (q + 1) : r * (q + 1) + (xcd - r) * q);
    const int ni = swz / nm, mi = swz - ni * nm;
    const int m0 = mi << 7, n0 = ni << 7;

    // staging: slot s = tid+256j (j=0..3); row = s>>3, col = s&7 (16B slots);
    // dest is LINEAR (wave-uniform base + lane*16), source k-group pre-XORed.
    const u16* pa[4]; const u16* pb[4]; int kmin[4];
    u16 *la[4], *lb[4];
    #pragma unroll
    for (int j = 0; j < 4; ++j) {
        int s = tid + j * 256;
        int row = s >> 3;
        int kg = ((s & 7) ^ swz8(row)) << 3;
        la[j] = As + ((s & ~63) << 3);
        lb[j] = Bs + ((s & ~63) << 3);
        pb[j] = Bt + (size_t)(n0 + row) * K + kg;
        kmin[j] = 0;
        if (MODE == 1) {
            int t = m0 + row, b = t >> 12, l = t & 4095;
            pa[j] = A + (((size_t)(b << 12) + (size_t)(l - 3)) << 10) + kg;
            kmin[j] = (3 - l) << 10;            // k0 < kmin -> tap reads zero pad
        } else if (MODE == 2) {
            int rg = m0 + row;
            int token = ((rg >> L2LC) << 12) + l0 + (rg & (LC - 1));
            pa[j] = A + ((size_t)token << 10) + kg;
        } else {
            pa[j] = A + (size_t)(m0 + row) * K + kg;
        }
    }

    f32x4 acc[4][4];
    #pragma unroll
    for (int a = 0; a < 4; ++a)
        #pragma unroll
        for (int b = 0; b < 4; ++b)
            #pragma unroll
            for (int rr = 0; rr < 4; ++rr) acc[a][b][rr] = 0.0f;

    // fragment ds_read offsets (u16 units) for ks=0; ks=1 = XOR 32 (slot bit2)
    int ra[4], rb[4];
    #pragma unroll
    for (int sm = 0; sm < 4; ++sm) {
        int rowa = wm * 64 + sm * 16 + (lane & 15);
        int rowb = wn * 64 + sm * 16 + (lane & 15);
        ra[sm] = (rowa << 6) + ((((lane >> 4) ^ swz8(rowa)) & 7) << 3);
        rb[sm] = (rowb << 6) + ((((lane >> 4) ^ swz8(rowb)) & 7) << 3);
    }

    const int nkb = K >> 6;
    for (int kb = 0; kb < nkb; ++kb) {
        const int k0 = kb << 6;
        __syncthreads();                         // prev iter's LDS reads done
        #pragma unroll
        for (int j = 0; j < 4; ++j) {
            const u16* ga = pa[j] + k0;
            if (MODE == 1) ga = (k0 < kmin[j]) ? zb : ga;
            gl16(ga, la[j]);
            gl16(pb[j] + k0, lb[j]);
        }
        __syncthreads();                         // barrier drains vmcnt -> tile ready

        #pragma unroll
        for (int ks = 0; ks < 2; ++ks) {
            const int kx = ks << 5;
            bf16x8 af[4], bfr[4];
            #pragma unroll
            for (int sm = 0; sm < 4; ++sm) af[sm] = *(const bf16x8*)(As + (ra[sm] ^ kx));
            #pragma unroll
            for (int sn = 0; sn < 4; ++sn) bfr[sn] = *(const bf16x8*)(Bs + (rb[sn] ^ kx));
            #pragma unroll
            for (int sm = 0; sm < 4; ++sm)
                #pragma unroll
                for (int sn = 0; sn < 4; ++sn)
                    acc[sm][sn] = __builtin_amdgcn_mfma_f32_16x16x32_bf16(af[sm], bfr[sn], acc[sm][sn], 0, 0, 0);
        }
    }

    int fl = 0;
    if (EPI == 3) fl = flag[0];
    // C/D layout: col=lane&15, row=(lane>>4)*4+reg
    #pragma unroll
    for (int sm = 0; sm < 4; ++sm) {
        #pragma unroll
        for (int sn = 0; sn < 4; ++sn) {
            int rbase = m0 + wm * 64 + sm * 16 + ((lane >> 4) * 4);
            int col   = n0 + wn * 64 + sn * 16 + (lane & 15);
            if (EPI == 2) {
                int bI = rbase >> L2LC, rloc = rbase & (LC - 1);
                int p = col >> 10, hh = col & 1023;
                size_t idx8 = ((((size_t)(bI * 3 + p) * LCG) + (rloc >> 3)) << 10) + hh;
                ushort4 o4;
                o4.x = f2b(acc[sm][sn][0]); o4.y = f2b(acc[sm][sn][1]);
                o4.z = f2b(acc[sm][sn][2]); o4.w = f2b(acc[sm][sn][3]);
                *(ushort4*)((u16*)outp + (idx8 << 3) + (rloc & 7)) = o4;
            } else {
                #pragma unroll
                for (int rr = 0; rr < 4; ++rr) {
                    int rowg = rbase + rr;
                    float v = acc[sm][sn][rr];
                    if (EPI == 0) {
                        ((u16*)outp)[(size_t)rowg * N + col] = f2b(v);
                    } else if (EPI == 1) {
                        ((u16*)outp)[(size_t)rowg * N + col] = f2b(v + P[P_CONVB + col]);
                    } else {
                        size_t gi = ((size_t)(tok0 + rowg) << 10) + col;
                        float xv = ldp(xorig, gi, fl);
                        float g = b2f(blend[gi]) * scale[tok0 + rowg] * P[P_RMS + col] * xv;
                        float o = v + P[P_LIN2B + col] + g;
                        if (fl) ((float*)outp)[gi] = o;
                        else    ((u16*)outp)[gi] = f2b(o);
                    }
                }
            }
        }
    }
}

template<int MODE, int EPI>
__global__ __launch_bounds__(256) void k_gemm(const u16* __restrict__ A, const u16* __restrict__ Bt,
                                              int N, int K, int nm, int l0, int tok0,
                                              const float* __restrict__ P,
                                              const u16* __restrict__ blend,
                                              const void* __restrict__ xorig,
                                              const float* __restrict__ scale,
                                              const int* __restrict__ flag,
                                              const u16* __restrict__ zb,
                                              void* __restrict__ outp) {
    gemm_core<MODE, EPI>(blockIdx.x, gridDim.x, A, Bt, N, K, nm, l0, tok0,
                         P, blend, xorig, scale, flag, zb, outp);
}

// ------------------------------------------------------------------
// SRU scan core; Uc grouped layout: ushort8 at ((b*3+p)*LCG+g)*1024 + h.
__device__ __forceinline__ void scan_core(int h, int b, const u16* __restrict__ Uc,
        const u16* __restrict__ cnnb, u16* xnblend, float* __restrict__ carry,
        const float* __restrict__ P, int l0, int first) {
    float vfv = P[P_VF + h], vrv = P[P_VR + h], bfv = P[P_BF + h], brv = P[P_BR + h], lamv = P[P_LAM + h];
    const float SXC = 1.00911627f;            // sqrt(1+exp(-4))
    float c = first ? 0.0f : carry[(b << 10) + h];
    const u16x8* U8 = (const u16x8*)Uc;
    size_t u0b = (((size_t)(b * 3 + 0) * LCG) << 10) + h;
    size_t u1b = (((size_t)(b * 3 + 1) * LCG) << 10) + h;
    size_t u2b = (((size_t)(b * 3 + 2) * LCG) << 10) + h;
    size_t gbase = (((size_t)(b * 4096 + l0)) << 10) + h;

    u16x8 a0[3], a1[3], a2[3];
    u16 bx[3][8], bc[3][8];
    #define SLOAD(g0, s) { \
        size_t gg = (size_t)(g0); \
        a0[s] = U8[u0b + (gg << 10)]; \
        a1[s] = U8[u1b + (gg << 10)]; \
        a2[s] = U8[u2b + (gg << 10)]; \
        _Pragma("unroll") \
        for (int j = 0; j < 8; ++j) { \
            size_t go = gbase + ((gg * 8 + j) << 10); \
            bx[s][j] = xnblend[go]; bc[s][j] = cnnb[go]; \
        } }
    #define SCOMP(g0, s) { \
        _Pragma("unroll") \
        for (int j = 0; j < 8; ++j) { \
            size_t go = gbase + (((size_t)(g0) * 8 + j) << 10); \
            float u0 = b2f(a0[s][j]), u1 = b2f(a1[s][j]), u2 = b2f(a2[s][j]); \
            float xn = b2f(bx[s][j]), cv = b2f(bc[s][j]); \
            float f = 1.0f / (1.0f + __expf(-(u1 + c * vfv + bfv))); \
            float cn = f * (c - u0) + u0; \
            float r_ = 1.0f / (1.0f + __expf(-(u2 + c * vrv + brv))); \
            float e2 = __expf(-2.0f * fabsf(cn)); \
            float th = (1.0f - e2) / (1.0f + e2); \
            th = (cn < 0.0f) ? -th : th; \
            float xr = xn * SXC; \
            float hh = r_ * (th - xr) + xr; \
            xnblend[go] = f2b(lamv * (cv - hh) + hh); \
            c = cn; \
        } }

    SLOAD(0, 0);
    SLOAD(1, 1);
    #pragma unroll 1
    for (int g = 0; g < LCG; g += 3) {
        if (g + 2 < LCG) SLOAD(g + 2, 2);
        SCOMP(g, 0);
        if (g + 3 < LCG) SLOAD(g + 3, 0);
        if (g + 1 < LCG) SCOMP(g + 1, 1);
        if (g + 4 < LCG) SLOAD(g + 4, 1);
        if (g + 2 < LCG) SCOMP(g + 2, 2);
    }
    carry[(b << 10) + h] = c;
    #undef SLOAD
    #undef SCOMP
}

__global__ __launch_bounds__(256) void k_scan(const u16* __restrict__ Uc, const u16* __restrict__ cnnb,
                                              u16* xnblend, float* __restrict__ carry,
                                              const float* __restrict__ P, int l0, int first) {
    scan_core(blockIdx.x * 256 + threadIdx.x, blockIdx.y, Uc, cnnb, xnblend, carry, P, l0, first);
}

// Fused: blocks [0,32) run scan(ch-1) on UcPrev; blocks [32,800) run the
// U GEMM(ch) into UcCur. Independent data; scan rides free in spare wave slots.
__global__ __launch_bounds__(256) void k_uscan(const u16* __restrict__ xnb, const u16* __restrict__ WsruT,
                                               int l0g, u16* __restrict__ UcCur,
                                               const u16* __restrict__ UcPrev, const u16* __restrict__ cnnb,
                                               float* __restrict__ carry, int l0s, int first,
                                               const float* __restrict__ P, const int* __restrict__ flag,
                                               const u16* __restrict__ zb) {
    if (blockIdx.x < 32) {
        int sb = blockIdx.x;
        scan_core((sb & 3) * 256 + threadIdx.x, sb >> 2, UcPrev, cnnb,
                  (u16*)xnb, carry, P, l0s, first);
    } else {
        gemm_core<2, 2>(blockIdx.x - 32, 768, xnb, WsruT, 3072, 1024, 32, l0g, 0,
                        P, nullptr, nullptr, nullptr, flag, zb, (void*)UcCur);
    }
}

// ------------------------------------------------------------------
__device__ __forceinline__ void breduce2(float& a, float& b, volatile float* sa, volatile float* sb, int tid) {
    #pragma unroll
    for (int m = 32; m; m >>= 1) { a += __shfl_xor(a, m, 64); b += __shfl_xor(b, m, 64); }
    int lane = tid & 63, wid = tid >> 6;
    if (lane == 0) { sa[wid] = a; sb[wid] = b; }
    __syncthreads();
    a = sa[0] + sa[1] + sa[2] + sa[3];
    b = sb[0] + sb[1] + sb[2] + sb[3];
    __syncthreads();
}

__global__ __launch_bounds__(256) void k_ln(const u16* __restrict__ cnnb, const float* __restrict__ P,
                                            u16* __restrict__ xnb) {
    __shared__ float sred[8];
    int t = blockIdx.x, tid = threadIdx.x;
    ushort4 cv = ((const ushort4*)(cnnb + ((size_t)t << 10)))[tid];
    float v0 = b2f(cv.x), v1 = b2f(cv.y), v2 = b2f(cv.z), v3 = b2f(cv.w);
    float s = v0 + v1 + v2 + v3;
    float ss = v0 * v0 + v1 * v1 + v2 * v2 + v3 * v3;
    breduce2(s, ss, sred, sred + 4, tid);
    float m = s * (1.0f / 1024.0f);
    float var = ss * (1.0f / 1024.0f) - m * m;
    float rs = rsqrtf(var + 1e-5f);
    int c = tid * 4;
    ushort4 o;
    o.x = f2b((v0 - m) * rs * P[P_LNW + c + 0] + P[P_LNB + c + 0]);
    o.y = f2b((v1 - m) * rs * P[P_LNW + c + 1] + P[P_LNB + c + 1]);
    o.z = f2b((v2 - m) * rs * P[P_LNW + c + 2] + P[P_LNB + c + 2]);
    o.w = f2b((v3 - m) * rs * P[P_LNW + c + 3] + P[P_LNB + c + 3]);
    ((ushort4*)(xnb + ((size_t)t << 10)))[tid] = o;
}

// ------------------------------------------------------------------
__global__ __launch_bounds__(256) void k_rms_ln1(const u16* __restrict__ blend, const void* __restrict__ x,
                                                 const float* __restrict__ P, const int* __restrict__ flag,
                                                 float* __restrict__ scale, u16* __restrict__ A1) {
    __shared__ float sred[8];
    int t = blockIdx.x, tid = threadIdx.x, fl = flag[0];
    ushort4 bv = ((const ushort4*)(blend + ((size_t)t << 10)))[tid];
    float b0 = b2f(bv.x), b1 = b2f(bv.y), b2 = b2f(bv.z), b3 = b2f(bv.w);
    float ss = b0 * b0 + b1 * b1 + b2 * b2 + b3 * b3, dummy = 0.0f;
    breduce2(ss, dummy, sred, sred + 4, tid);
    float sc = rsqrtf(ss * (1.0f / 1024.0f) + 1e-6f);
    if (tid == 0) scale[t] = sc;
    size_t gb = ((size_t)t << 10) + tid * 4;
    int c = tid * 4;
    float g0 = b0 * sc * P[P_RMS + c + 0] * ldp(x, gb + 0, fl);
    float g1 = b1 * sc * P[P_RMS + c + 1] * ldp(x, gb + 1, fl);
    float g2 = b2 * sc * P[P_RMS + c + 2] * ldp(x, gb + 2, fl);
    float g3 = b3 * sc * P[P_RMS + c + 3] * ldp(x, gb + 3, fl);
    float s2 = g0 + g1 + g2 + g3;
    float ss2 = g0 * g0 + g1 * g1 + g2 * g2 + g3 * g3;
    breduce2(s2, ss2, sred, sred + 4, tid);
    float m = s2 * (1.0f / 1024.0f);
    float var = ss2 * (1.0f / 1024.0f) - m * m;
    float rs = rsqrtf(var + 1e-5f);
    ushort4 o;
    o.x = f2b(gelu_exact((g0 - m) * rs * P[P_LN1W + c + 0] + P[P_LN1B + c + 0]));
    o.y = f2b(gelu_exact((g1 - m) * rs * P[P_LN1W + c + 1] + P[P_LN1B + c + 1]));
    o.z = f2b(gelu_exact((g2 - m) * rs * P[P_LN1W + c + 2] + P[P_LN1B + c + 2]));
    o.w = f2b(gelu_exact((g3 - m) * rs * P[P_LN1W + c + 3] + P[P_LN1B + c + 3]));
    ((ushort4*)(A1 + ((size_t)t << 10)))[tid] = o;
}

__global__ __launch_bounds__(256) void k_ln2_gelu(const u16* __restrict__ T1c, const float* __restrict__ P,
                                                  u16* __restrict__ A2c) {
    __shared__ float sred[8];
    int t = blockIdx.x, tid = threadIdx.x;
    const ushort4* tp = (const ushort4*)(T1c + ((size_t)t << 11));
    ushort4 va = tp[tid * 2], vb = tp[tid * 2 + 1];
    float e[8] = { b2f(va.x), b2f(va.y), b2f(va.z), b2f(va.w),
                   b2f(vb.x), b2f(vb.y), b2f(vb.z), b2f(vb.w) };
    float s = 0.0f, ss = 0.0f;
    #pragma unroll
    for (int i = 0; i < 8; ++i) { s += e[i]; ss += e[i] * e[i]; }
    breduce2(s, ss, sred, sred + 4, tid);
    float m = s * (1.0f / 2048.0f);
    float var = ss * (1.0f / 2048.0f) - m * m;
    float rs = rsqrtf(var + 1e-5f);
    int c = tid * 8;
    u16 oo[8];
    #pragma unroll
    for (int i = 0; i < 8; ++i)
        oo[i] = f2b(gelu_exact((e[i] - m) * rs * P[P_LN2W + c + i] + P[P_LN2B + c + i]));
    ushort4 oa, ob;
    oa.x = oo[0]; oa.y = oo[1]; oa.z = oo[2]; oa.w = oo[3];
    ob.x = oo[4]; ob.y = oo[5]; ob.z = oo[6]; ob.w = oo[7];
    ushort4* op = (ushort4*)(A2c + ((size_t)t << 11));
    op[tid * 2] = oa; op[tid * 2 + 1] = ob;
}

// ------------------------------------------------------------------
extern "C" void kernel_launch(void* const* d_in, const int* in_sizes, int n_in,
                              void* d_out, int out_size, void* d_ws, size_t ws_size,
                              hipStream_t stream) {
    (void)in_sizes; (void)n_in; (void)out_size;
    const void* x        = d_in[0];
    const void* conv_w   = d_in[1];
    const void* conv_b   = d_in[2];
    const void* sru_ln_w = d_in[3];
    const void* sru_ln_b = d_in[4];
    const void* sru_W    = d_in[5];
    const void* sru_vf   = d_in[6];
    const void* sru_vr   = d_in[7];
    const void* sru_bf   = d_in[8];
    const void* sru_br   = d_in[9];
    const void* lambda_w = d_in[10];
    const void* rms_w    = d_in[11];
    const void* ln1_w    = d_in[12];
    const void* ln1_b    = d_in[13];
    const void* lin1_w   = d_in[14];
    const void* ln2_w    = d_in[15];
    const void* ln2_b    = d_in[16];
    const void* lin2_w   = d_in[17];
    const void* lin2_b   = d_in[18];

    if (ws_size < WS_REQ) {
        float sv = 1000.0f + (float)(ws_size >> 20);
        k_fill<<<16384, 256, 0, stream>>>((float*)d_out, sv);
        return;
    }

    char* ws = (char*)d_ws;
    u16*   xb    = (u16*)(ws + OFF_XB);
    u16*   cnnb  = (u16*)(ws + OFF_CNNB);
    u16*   xnb   = (u16*)(ws + OFF_XNB);
    u16*   UcA   = (u16*)(ws + OFF_XB);           // 24 MiB; xb dead after conv
    u16*   UcB   = (u16*)(ws + OFF_UCB);          // 24 MiB
    u16*   WcT   = (u16*)(ws + OFF_WCT);
    u16*   WsruT = (u16*)(ws + OFF_WSRUT);
    u16*   W1T   = (u16*)(ws + OFF_W1T);
    u16*   W2T   = (u16*)(ws + OFF_W2T);
    float* carry = (float*)(ws + OFF_CARRY);
    float* P     = (float*)(ws + OFF_P);
    float* scale = (float*)(ws + OFF_SCALE);
    int*   flag  = (int*)(ws + OFF_FLAG);
    float* zbuf  = (float*)(ws + OFF_ZERO);
    const u16* zb16 = (const u16*)zbuf;
    u16*   A1  = xb;                              // Uc dead after last scan
    u16*   T1c = (u16*)(ws + OFF_U4C);            // 32 MiB
    u16*   A2  = cnnb;                            // 64 MiB (2 chunks of 8192 rows)

    k_detect<<<1, 256, 0, stream>>>((const u16*)x, flag);
    k_params<<<64, 256, 0, stream>>>(flag, conv_b, sru_ln_w, sru_ln_b, sru_vf, sru_vr,
                                     sru_bf, sru_br, lambda_w, rms_w, ln1_w, ln1_b,
                                     lin2_b, ln2_w, ln2_b, P, zbuf);
    k_x2b<<<32768, 256, 0, stream>>>(flag, x, xb);
    k_conv_reorder<<<1024, 256, 0, stream>>>(flag, conv_w, WcT);
    // conv: M=32768 N=1024 K=4096 -> 256x8 = 2048 tiles, nm=256
    k_gemm<1, 1><<<2048, 256, 0, stream>>>(xb, WcT, 1024, 4096, 256, 0, 0,
                                           P, nullptr, nullptr, nullptr, flag, zb16, cnnb);
    k_ln<<<32768, 256, 0, stream>>>(cnnb, P, xnb);
    k_transpose_t<<<dim3(48, 16), 256, 0, stream>>>(flag, sru_W, WsruT, 1024, 3072);
    // U chunks (LC=512) fused with previous chunk's scan; nm=32
    k_gemm<2, 2><<<768, 256, 0, stream>>>(xnb, WsruT, 3072, 1024, 32, 0, 0,
                                          P, nullptr, nullptr, nullptr, flag, zb16, UcA);
    for (int ch = 1; ch < NCH; ++ch) {
        u16* cur  = (ch & 1) ? UcB : UcA;
        u16* prev = (ch & 1) ? UcA : UcB;
        k_uscan<<<800, 256, 0, stream>>>(xnb, WsruT, ch * LC, cur, prev, cnnb,
                                         carry, (ch - 1) * LC, ch == 1, P, flag, zb16);
    }
    k_scan<<<dim3(4, 8), 256, 0, stream>>>(UcB, cnnb, xnb, carry, P, (NCH - 1) * LC, 0);
    k_rms_ln1<<<32768, 256, 0, stream>>>(xnb, x, P, flag, scale, A1);
    k_transpose_t<<<dim3(32, 16), 256, 0, stream>>>(flag, lin1_w, W1T, 1024, 2048);
    k_transpose_t<<<dim3(16, 32), 256, 0, stream>>>(flag, lin2_w, W2T, 2048, 1024);
    // FFN: G1+ln2 per 8192-token chunk (nm=64); G2 merged over 16384 tokens (nm=128)
    for (int p = 0; p < 2; ++p) {
        int base = p * 16384;
        for (int h = 0; h < 2; ++h) {
            int tok0 = base + h * MC;
            k_gemm<0, 0><<<1024, 256, 0, stream>>>(A1 + ((size_t)tok0 << 10), W1T, 2048, 1024, 64, 0, 0,
                                                   P, nullptr, nullptr, nullptr, flag, zb16, T1c);
            k_ln2_gelu<<<MC, 256, 0, stream>>>(T1c, P, A2 + ((size_t)(h * MC) << 11));
        }
        // G2: M=16384 N=1024 K=2048 -> 128x8 = 1024 tiles
        k_gemm<0, 3><<<1024, 256, 0, stream>>>(A2, W2T, 1024, 2048, 128, 0, base,
                                               P, xnb, x, scale, flag, zb16, d_out);
    }
}

// Round 6
// 2514.786 us; speedup vs baseline: 2.0376x; 1.0125x over previous
//
#include <hip/hip_runtime.h>

typedef unsigned short u16;
typedef short bf16x8 __attribute__((ext_vector_type(8)));
typedef float f32x4 __attribute__((ext_vector_type(4)));
typedef unsigned short u16x8 __attribute__((ext_vector_type(8)));

#define LC 512            // L-chunk for U/scan
#define L2LC 9
#define LCG 64            // LC/8 groups
#define NCH 8             // 4096 / LC
#define MC 8192           // token chunk for FFN G1

// workspace offsets (bytes)
#define OFF_XB     0ull              // 64 MiB  bf16 x -> UcA(24M)+UcB(24M) -> A1
#define OFF_UCB    25165824ull       // Uc double buffer B
#define OFF_CNNB   67108864ull       // 64 MiB  cnn bf16 -> later A2 (64M)
#define OFF_XNB    134217728ull      // 64 MiB  xn bf16 -> blend (in place)
#define OFF_U4C    201326592ull      // 32 MiB  T1c
#define OFF_WCT    234881024ull      // 8 MiB
#define OFF_WSRUT  243269632ull      // 6 MiB
#define OFF_W1T    249561088ull      // 4 MiB
#define OFF_W2T    253755392ull      // 4 MiB
#define OFF_CARRY  257949696ull      // 32 KiB f32[8192]
#define OFF_P      257982464ull      // 64 KiB param block f32[16384]
#define OFF_SCALE  258048000ull      // 128 KiB f32[32768]
#define OFF_FLAG   258179072ull      // int
#define OFF_ZERO   258179328ull      // 128 B zero pad for im2col OOB lanes
#define WS_REQ     258183168ull

// param-block offsets (floats)
#define P_CONVB 0
#define P_LNW   1024
#define P_LNB   2048
#define P_VF    3072
#define P_VR    4096
#define P_BF    5120
#define P_BR    6144
#define P_LAM   7168
#define P_RMS   8192
#define P_LN1W  9216
#define P_LN1B  10240
#define P_LIN2B 11264
#define P_LN2W  12288
#define P_LN2B  14336

__device__ __forceinline__ float b2f(u16 u) {
    union { unsigned int i; float f; } v; v.i = ((unsigned int)u) << 16; return v.f;
}
__device__ __forceinline__ u16 f2b(float f) {
    union { float f; unsigned int i; } v; v.f = f;
    unsigned int r = v.i + 0x7fffu + ((v.i >> 16) & 1u);
    return (u16)(r >> 16);
}
__device__ __forceinline__ float ldp(const void* p, size_t i, int fl) {
    return fl ? ((const float*)p)[i] : b2f(((const u16*)p)[i]);
}
__device__ __forceinline__ float gelu_exact(float a) {
    return 0.5f * a * (1.0f + erff(a * 0.70710678118654752f));
}

// async global->LDS, 16B per lane; dest = wave-uniform base + lane*16
typedef const __attribute__((address_space(1))) void gas_void;
typedef __attribute__((address_space(3))) void las_void;
__device__ __forceinline__ void gl16(const u16* g, u16* l) {
    __builtin_amdgcn_global_load_lds((gas_void*)g, (las_void*)l, 16, 0, 0);
}

// 8-slot XOR swizzle over [128][64] u16 rows (8 x 16B slots per row):
// slot' = slot ^ swz8(row). Applied on BOTH the staging source (pre-XOR of
// per-lane global k-offset) and the frag ds_read (rule 21).
__device__ __forceinline__ int swz8(int row) { return (row + (row >> 3)) & 7; }

// ------------------------------------------------------------------
__global__ __launch_bounds__(256) void k_fill(float* out, float v) {
    size_t i = ((size_t)blockIdx.x * 256 + threadIdx.x) * 4;
    float4 o; o.x = v; o.y = v; o.z = v; o.w = v;
    *(float4*)(out + i) = o;
}

// dtype detect: for f32 data the EVEN u16 of each pair is the low mantissa
// half -> random bits -> wild exponents/NaN when read as bf16.
__global__ void k_detect(const u16* __restrict__ x, int* __restrict__ flag) {
    __shared__ int cnt[4];
    int tid = threadIdx.x;
    int c = 0;
    for (int i = 0; i < 16; ++i) {
        float f = b2f(x[2 * (tid * 16 + i)]);
        if (f != f || fabsf(f) > 1e6f) c++;
    }
    #pragma unroll
    for (int m = 32; m; m >>= 1) c += __shfl_xor(c, m, 64);
    if ((tid & 63) == 0) cnt[tid >> 6] = c;
    __syncthreads();
    if (tid == 0) flag[0] = (cnt[0] + cnt[1] + cnt[2] + cnt[3] > 100) ? 1 : 0;
}

__global__ __launch_bounds__(256) void k_params(const int* __restrict__ flag,
        const void* conv_b, const void* lnw, const void* lnb,
        const void* vf, const void* vr, const void* bf, const void* br,
        const void* lam, const void* rms, const void* ln1w, const void* ln1b,
        const void* lin2b, const void* ln2w, const void* ln2b,
        float* __restrict__ P, float* __restrict__ Z) {
    if (blockIdx.x == 0 && threadIdx.x < 32) Z[threadIdx.x] = 0.0f;
    int idx = blockIdx.x * 256 + threadIdx.x;   // 0..16383
    int fl = flag[0];
    int vec = idx >> 10, off = idx & 1023;
    const void* src; size_t so = off;
    switch (vec) {
        case 0: src = conv_b; break;
        case 1: src = lnw; break;
        case 2: src = lnb; break;
        case 3: src = vf; break;
        case 4: src = vr; break;
        case 5: src = bf; break;
        case 6: src = br; break;
        case 7: src = lam; break;
        case 8: src = rms; break;
        case 9: src = ln1w; break;
        case 10: src = ln1b; break;
        case 11: src = lin2b; break;
        case 12: case 13: src = ln2w; so = idx - P_LN2W; break;
        default: src = ln2b; so = idx - P_LN2B; break;
    }
    P[idx] = ldp(src, so, fl);
}

__global__ __launch_bounds__(256) void k_x2b(const int* __restrict__ flag,
                                             const void* __restrict__ x, u16* __restrict__ xb) {
    size_t i = (size_t)blockIdx.x * 256 + threadIdx.x;
    int fl = flag[0];
    ushort4 o;
    if (fl) {
        float4 v = ((const float4*)x)[i];
        o.x = f2b(v.x); o.y = f2b(v.y); o.z = f2b(v.z); o.w = f2b(v.w);
    } else {
        o = ((const ushort4*)x)[i];
    }
    ((ushort4*)xb)[i] = o;
}

// conv_w (O,I,K=4) -> WcT[o][k*1024+i] bf16; coalesced 16B/8B reads per channel
__global__ __launch_bounds__(256) void k_conv_reorder(const int* __restrict__ flag,
                                                      const void* __restrict__ w, u16* __restrict__ out) {
    int o = blockIdx.x, fl = flag[0];
    for (int i = threadIdx.x; i < 1024; i += 256) {
        float f0, f1, f2, f3;
        if (fl) {
            float4 v = ((const float4*)w)[(size_t)o * 1024 + i];
            f0 = v.x; f1 = v.y; f2 = v.z; f3 = v.w;
        } else {
            ushort4 v = ((const ushort4*)w)[(size_t)o * 1024 + i];
            f0 = b2f(v.x); f1 = b2f(v.y); f2 = b2f(v.z); f3 = b2f(v.w);
        }
        size_t ob = (size_t)o * 4096 + i;
        out[ob]        = f2b(f0);
        out[ob + 1024] = f2b(f1);
        out[ob + 2048] = f2b(f2);
        out[ob + 3072] = f2b(f3);
    }
}

// LDS-tiled transpose+cast: in [R][C] -> out [C][R] bf16, 64x64 tiles.
__global__ __launch_bounds__(256) void k_transpose_t(const int* __restrict__ flag,
                                                     const void* __restrict__ in, u16* __restrict__ out,
                                                     int R, int C) {
    __shared__ float tile[64][65];
    int fl = flag[0];
    int c0 = blockIdx.x * 64, r0 = blockIdx.y * 64;
    int tx = threadIdx.x & 63, ty = threadIdx.x >> 6;
    #pragma unroll
    for (int i = 0; i < 16; ++i) {
        int row = i * 4 + ty;
        tile[row][tx] = ldp(in, (size_t)(r0 + row) * C + c0 + tx, fl);
    }
    __syncthreads();
    #pragma unroll
    for (int i = 0; i < 16; ++i) {
        int col = i * 4 + ty;
        out[(size_t)(c0 + col) * R + r0 + tx] = f2b(tile[tx][col]);
    }
}

// ------------------------------------------------------------------
// GEMM core C[M,N]=A[M,K]*Bt[N,K]^T, bf16 MFMA 16x16x32, 128x128 tile, BK=64.
// m97 structure: global_load_lds(16B) staging, 8-slot-XOR-swizzled LDS,
// 2 barriers per 64-K step. m-MAJOR XCD chunking: each XCD owns a contiguous
// m-range (its A slice fetched once); B re-walked per m-panel, L2-absorbed.
// MODE 0: plain A rows. MODE 1: conv im2col (zero-pad taps via zb).
// MODE 2: chunked-U row remap token=((row>>L2LC)<<12)+l0+(row&(LC-1)).
// EPI 0: bf16 out. EPI 1: +conv_b bf16. EPI 2: grouped-U scatter
//   [b*3+p][r>>3][h][8]. EPI 3: +lin2_b + gated residual.
template<int MODE, int EPI>
__device__ __forceinline__ void gemm_core(int bid, int nwg,
        const u16* __restrict__ A, const u16* __restrict__ Bt,
        int N, int K, int nn, int l0, int tok0,
        const float* __restrict__ P, const u16* __restrict__ blend,
        const void* __restrict__ xorig, const float* __restrict__ scale,
        const int* __restrict__ flag, const u16* __restrict__ zb,
        void* __restrict__ outp) {
    __shared__ __align__(16) u16 As[128 * 64];
    __shared__ __align__(16) u16 Bs[128 * 64];
    const int tid = threadIdx.x;
    const int lane = tid & 63;
    const int wid = tid >> 6;
    const int wm = wid >> 1, wn = wid & 1;

    // XCD-chunked bijective swizzle (m204), m-major decode
    const int q = nwg >> 3, r = nwg & 7;
    const int xcd = bid & 7, idx = bid >> 3;
    const int swz = idx + (xcd < r ? xcd * (q + 1) : r * (q + 1) + (xcd - r) * q);
    const int mi = swz / nn, ni = swz - mi * nn;
    const int m0 = mi << 7, n0 = ni << 7;

    // staging: slot s = tid+256j (j=0..3); row = s>>3, col = s&7 (16B slots);
    // dest is LINEAR (wave-uniform base + lane*16), source k-group pre-XORed.
    const u16* pa[4]; const u16* pb[4]; int kmin[4];
    u16 *la[4], *lb[4];
    #pragma unroll
    for (int j = 0; j < 4; ++j) {
        int s = tid + j * 256;
        int row = s >> 3;
        int kg = ((s & 7) ^ swz8(row)) << 3;
        la[j] = As + ((s & ~63) << 3);
        lb[j] = Bs + ((s & ~63) << 3);
        pb[j] = Bt + (size_t)(n0 + row) * K + kg;
        kmin[j] = 0;
        if (MODE == 1) {
            int t = m0 + row, b = t >> 12, l = t & 4095;
            pa[j] = A + (((size_t)(b << 12) + (size_t)(l - 3)) << 10) + kg;
            kmin[j] = (3 - l) << 10;            // k0 < kmin -> tap reads zero pad
        } else if (MODE == 2) {
            int rg = m0 + row;
            int token = ((rg >> L2LC) << 12) + l0 + (rg & (LC - 1));
            pa[j] = A + ((size_t)token << 10) + kg;
        } else {
            pa[j] = A + (size_t)(m0 + row) * K + kg;
        }
    }

    f32x4 acc[4][4];
    #pragma unroll
    for (int a = 0; a < 4; ++a)
        #pragma unroll
        for (int b = 0; b < 4; ++b)
            #pragma unroll
            for (int rr = 0; rr < 4; ++rr) acc[a][b][rr] = 0.0f;

    // fragment ds_read offsets (u16 units) for ks=0; ks=1 = XOR 32 (slot bit2)
    int ra[4], rb[4];
    #pragma unroll
    for (int sm = 0; sm < 4; ++sm) {
        int rowa = wm * 64 + sm * 16 + (lane & 15);
        int rowb = wn * 64 + sm * 16 + (lane & 15);
        ra[sm] = (rowa << 6) + ((((lane >> 4) ^ swz8(rowa)) & 7) << 3);
        rb[sm] = (rowb << 6) + ((((lane >> 4) ^ swz8(rowb)) & 7) << 3);
    }

    const int nkb = K >> 6;
    for (int kb = 0; kb < nkb; ++kb) {
        const int k0 = kb << 6;
        __syncthreads();                         // prev iter's LDS reads done
        #pragma unroll
        for (int j = 0; j < 4; ++j) {
            const u16* ga = pa[j] + k0;
            if (MODE == 1) ga = (k0 < kmin[j]) ? zb : ga;
            gl16(ga, la[j]);
            gl16(pb[j] + k0, lb[j]);
        }
        __syncthreads();                         // barrier drains vmcnt -> tile ready

        #pragma unroll
        for (int ks = 0; ks < 2; ++ks) {
            const int kx = ks << 5;
            bf16x8 af[4], bfr[4];
            #pragma unroll
            for (int sm = 0; sm < 4; ++sm) af[sm] = *(const bf16x8*)(As + (ra[sm] ^ kx));
            #pragma unroll
            for (int sn = 0; sn < 4; ++sn) bfr[sn] = *(const bf16x8*)(Bs + (rb[sn] ^ kx));
            #pragma unroll
            for (int sm = 0; sm < 4; ++sm)
                #pragma unroll
                for (int sn = 0; sn < 4; ++sn)
                    acc[sm][sn] = __builtin_amdgcn_mfma_f32_16x16x32_bf16(af[sm], bfr[sn], acc[sm][sn], 0, 0, 0);
        }
    }

    int fl = 0;
    if (EPI == 3) fl = flag[0];
    // C/D layout: col=lane&15, row=(lane>>4)*4+reg
    #pragma unroll
    for (int sm = 0; sm < 4; ++sm) {
        #pragma unroll
        for (int sn = 0; sn < 4; ++sn) {
            int rbase = m0 + wm * 64 + sm * 16 + ((lane >> 4) * 4);
            int col   = n0 + wn * 64 + sn * 16 + (lane & 15);
            if (EPI == 2) {
                int bI = rbase >> L2LC, rloc = rbase & (LC - 1);
                int p = col >> 10, hh = col & 1023;
                size_t idx8 = ((((size_t)(bI * 3 + p) * LCG) + (rloc >> 3)) << 10) + hh;
                ushort4 o4;
                o4.x = f2b(acc[sm][sn][0]); o4.y = f2b(acc[sm][sn][1]);
                o4.z = f2b(acc[sm][sn][2]); o4.w = f2b(acc[sm][sn][3]);
                *(ushort4*)((u16*)outp + (idx8 << 3) + (rloc & 7)) = o4;
            } else {
                #pragma unroll
                for (int rr = 0; rr < 4; ++rr) {
                    int rowg = rbase + rr;
                    float v = acc[sm][sn][rr];
                    if (EPI == 0) {
                        ((u16*)outp)[(size_t)rowg * N + col] = f2b(v);
                    } else if (EPI == 1) {
                        ((u16*)outp)[(size_t)rowg * N + col] = f2b(v + P[P_CONVB + col]);
                    } else {
                        size_t gi = ((size_t)(tok0 + rowg) << 10) + col;
                        float xv = ldp(xorig, gi, fl);
                        float g = b2f(blend[gi]) * scale[tok0 + rowg] * P[P_RMS + col] * xv;
                        float o = v + P[P_LIN2B + col] + g;
                        if (fl) ((float*)outp)[gi] = o;
                        else    ((u16*)outp)[gi] = f2b(o);
                    }
                }
            }
        }
    }
}

template<int MODE, int EPI>
__global__ __launch_bounds__(256) void k_gemm(const u16* __restrict__ A, const u16* __restrict__ Bt,
                                              int N, int K, int nn, int l0, int tok0,
                                              const float* __restrict__ P,
                                              const u16* __restrict__ blend,
                                              const void* __restrict__ xorig,
                                              const float* __restrict__ scale,
                                              const int* __restrict__ flag,
                                              const u16* __restrict__ zb,
                                              void* __restrict__ outp) {
    gemm_core<MODE, EPI>(blockIdx.x, gridDim.x, A, Bt, N, K, nn, l0, tok0,
                         P, blend, xorig, scale, flag, zb, outp);
}

// ------------------------------------------------------------------
// SRU scan core; Uc grouped layout: ushort8 at ((b*3+p)*LCG+g)*1024 + h.
__device__ __forceinline__ void scan_core(int h, int b, const u16* __restrict__ Uc,
        const u16* __restrict__ cnnb, u16* xnblend, float* __restrict__ carry,
        const float* __restrict__ P, int l0, int first) {
    float vfv = P[P_VF + h], vrv = P[P_VR + h], bfv = P[P_BF + h], brv = P[P_BR + h], lamv = P[P_LAM + h];
    const float SXC = 1.00911627f;            // sqrt(1+exp(-4))
    float c = first ? 0.0f : carry[(b << 10) + h];
    const u16x8* U8 = (const u16x8*)Uc;
    size_t u0b = (((size_t)(b * 3 + 0) * LCG) << 10) + h;
    size_t u1b = (((size_t)(b * 3 + 1) * LCG) << 10) + h;
    size_t u2b = (((size_t)(b * 3 + 2) * LCG) << 10) + h;
    size_t gbase = (((size_t)(b * 4096 + l0)) << 10) + h;

    u16x8 a0[3], a1[3], a2[3];
    u16 bx[3][8], bc[3][8];
    #define SLOAD(g0, s) { \
        size_t gg = (size_t)(g0); \
        a0[s] = U8[u0b + (gg << 10)]; \
        a1[s] = U8[u1b + (gg << 10)]; \
        a2[s] = U8[u2b + (gg << 10)]; \
        _Pragma("unroll") \
        for (int j = 0; j < 8; ++j) { \
            size_t go = gbase + ((gg * 8 + j) << 10); \
            bx[s][j] = xnblend[go]; bc[s][j] = cnnb[go]; \
        } }
    #define SCOMP(g0, s) { \
        _Pragma("unroll") \
        for (int j = 0; j < 8; ++j) { \
            size_t go = gbase + (((size_t)(g0) * 8 + j) << 10); \
            float u0 = b2f(a0[s][j]), u1 = b2f(a1[s][j]), u2 = b2f(a2[s][j]); \
            float xn = b2f(bx[s][j]), cv = b2f(bc[s][j]); \
            float f = 1.0f / (1.0f + __expf(-(u1 + c * vfv + bfv))); \
            float cn = f * (c - u0) + u0; \
            float r_ = 1.0f / (1.0f + __expf(-(u2 + c * vrv + brv))); \
            float e2 = __expf(-2.0f * fabsf(cn)); \
            float th = (1.0f - e2) / (1.0f + e2); \
            th = (cn < 0.0f) ? -th : th; \
            float xr = xn * SXC; \
            float hh = r_ * (th - xr) + xr; \
            xnblend[go] = f2b(lamv * (cv - hh) + hh); \
            c = cn; \
        } }

    SLOAD(0, 0);
    SLOAD(1, 1);
    #pragma unroll 1
    for (int g = 0; g < LCG; g += 3) {
        if (g + 2 < LCG) SLOAD(g + 2, 2);
        SCOMP(g, 0);
        if (g + 3 < LCG) SLOAD(g + 3, 0);
        if (g + 1 < LCG) SCOMP(g + 1, 1);
        if (g + 4 < LCG) SLOAD(g + 4, 1);
        if (g + 2 < LCG) SCOMP(g + 2, 2);
    }
    carry[(b << 10) + h] = c;
    #undef SLOAD
    #undef SCOMP
}

// standalone scan: 64-thread blocks, grid (16, 8) -> 128 CUs engaged
__global__ __launch_bounds__(64) void k_scan(const u16* __restrict__ Uc, const u16* __restrict__ cnnb,
                                             u16* xnblend, float* __restrict__ carry,
                                             const float* __restrict__ P, int l0, int first) {
    scan_core(blockIdx.x * 64 + threadIdx.x, blockIdx.y, Uc, cnnb, xnblend, carry, P, l0, first);
}

// Fused: blocks [0,128) run scan(ch-1) on UcPrev (64 active lanes each; the
// other 3 waves exit immediately, freeing slots); blocks [128,896) run the
// U GEMM(ch) into UcCur. Disjoint data; scan hides under the GEMM.
__global__ __launch_bounds__(256) void k_uscan(const u16* __restrict__ xnb, const u16* __restrict__ WsruT,
                                               int l0g, u16* __restrict__ UcCur,
                                               const u16* __restrict__ UcPrev, const u16* __restrict__ cnnb,
                                               float* __restrict__ carry, int l0s, int first,
                                               const float* __restrict__ P, const int* __restrict__ flag,
                                               const u16* __restrict__ zb) {
    if (blockIdx.x < 128) {
        if (threadIdx.x < 64) {
            int sb = blockIdx.x;
            scan_core((sb & 15) * 64 + threadIdx.x, sb >> 4, UcPrev, cnnb,
                      (u16*)xnb, carry, P, l0s, first);
        }
    } else {
        gemm_core<2, 2>(blockIdx.x - 128, 768, xnb, WsruT, 3072, 1024, 24, l0g, 0,
                        P, nullptr, nullptr, nullptr, flag, zb, (void*)UcCur);
    }
}

// ------------------------------------------------------------------
__device__ __forceinline__ void breduce2(float& a, float& b, volatile float* sa, volatile float* sb, int tid) {
    #pragma unroll
    for (int m = 32; m; m >>= 1) { a += __shfl_xor(a, m, 64); b += __shfl_xor(b, m, 64); }
    int lane = tid & 63, wid = tid >> 6;
    if (lane == 0) { sa[wid] = a; sb[wid] = b; }
    __syncthreads();
    a = sa[0] + sa[1] + sa[2] + sa[3];
    b = sb[0] + sb[1] + sb[2] + sb[3];
    __syncthreads();
}

__global__ __launch_bounds__(256) void k_ln(const u16* __restrict__ cnnb, const float* __restrict__ P,
                                            u16* __restrict__ xnb) {
    __shared__ float sred[8];
    int t = blockIdx.x, tid = threadIdx.x;
    ushort4 cv = ((const ushort4*)(cnnb + ((size_t)t << 10)))[tid];
    float v0 = b2f(cv.x), v1 = b2f(cv.y), v2 = b2f(cv.z), v3 = b2f(cv.w);
    float s = v0 + v1 + v2 + v3;
    float ss = v0 * v0 + v1 * v1 + v2 * v2 + v3 * v3;
    breduce2(s, ss, sred, sred + 4, tid);
    float m = s * (1.0f / 1024.0f);
    float var = ss * (1.0f / 1024.0f) - m * m;
    float rs = rsqrtf(var + 1e-5f);
    int c = tid * 4;
    ushort4 o;
    o.x = f2b((v0 - m) * rs * P[P_LNW + c + 0] + P[P_LNB + c + 0]);
    o.y = f2b((v1 - m) * rs * P[P_LNW + c + 1] + P[P_LNB + c + 1]);
    o.z = f2b((v2 - m) * rs * P[P_LNW + c + 2] + P[P_LNB + c + 2]);
    o.w = f2b((v3 - m) * rs * P[P_LNW + c + 3] + P[P_LNB + c + 3]);
    ((ushort4*)(xnb + ((size_t)t << 10)))[tid] = o;
}

// ------------------------------------------------------------------
__global__ __launch_bounds__(256) void k_rms_ln1(const u16* __restrict__ blend, const void* __restrict__ x,
                                                 const float* __restrict__ P, const int* __restrict__ flag,
                                                 float* __restrict__ scale, u16* __restrict__ A1) {
    __shared__ float sred[8];
    int t = blockIdx.x, tid = threadIdx.x, fl = flag[0];
    ushort4 bv = ((const ushort4*)(blend + ((size_t)t << 10)))[tid];
    float b0 = b2f(bv.x), b1 = b2f(bv.y), b2 = b2f(bv.z), b3 = b2f(bv.w);
    float ss = b0 * b0 + b1 * b1 + b2 * b2 + b3 * b3, dummy = 0.0f;
    breduce2(ss, dummy, sred, sred + 4, tid);
    float sc = rsqrtf(ss * (1.0f / 1024.0f) + 1e-6f);
    if (tid == 0) scale[t] = sc;
    size_t gb = ((size_t)t << 10) + tid * 4;
    int c = tid * 4;
    float g0 = b0 * sc * P[P_RMS + c + 0] * ldp(x, gb + 0, fl);
    float g1 = b1 * sc * P[P_RMS + c + 1] * ldp(x, gb + 1, fl);
    float g2 = b2 * sc * P[P_RMS + c + 2] * ldp(x, gb + 2, fl);
    float g3 = b3 * sc * P[P_RMS + c + 3] * ldp(x, gb + 3, fl);
    float s2 = g0 + g1 + g2 + g3;
    float ss2 = g0 * g0 + g1 * g1 + g2 * g2 + g3 * g3;
    breduce2(s2, ss2, sred, sred + 4, tid);
    float m = s2 * (1.0f / 1024.0f);
    float var = ss2 * (1.0f / 1024.0f) - m * m;
    float rs = rsqrtf(var + 1e-5f);
    ushort4 o;
    o.x = f2b(gelu_exact((g0 - m) * rs * P[P_LN1W + c + 0] + P[P_LN1B + c + 0]));
    o.y = f2b(gelu_exact((g1 - m) * rs * P[P_LN1W + c + 1] + P[P_LN1B + c + 1]));
    o.z = f2b(gelu_exact((g2 - m) * rs * P[P_LN1W + c + 2] + P[P_LN1B + c + 2]));
    o.w = f2b(gelu_exact((g3 - m) * rs * P[P_LN1W + c + 3] + P[P_LN1B + c + 3]));
    ((ushort4*)(A1 + ((size_t)t << 10)))[tid] = o;
}

__global__ __launch_bounds__(256) void k_ln2_gelu(const u16* __restrict__ T1c, const float* __restrict__ P,
                                                  u16* __restrict__ A2c) {
    __shared__ float sred[8];
    int t = blockIdx.x, tid = threadIdx.x;
    const ushort4* tp = (const ushort4*)(T1c + ((size_t)t << 11));
    ushort4 va = tp[tid * 2], vb = tp[tid * 2 + 1];
    float e[8] = { b2f(va.x), b2f(va.y), b2f(va.z), b2f(va.w),
                   b2f(vb.x), b2f(vb.y), b2f(vb.z), b2f(vb.w) };
    float s = 0.0f, ss = 0.0f;
    #pragma unroll
    for (int i = 0; i < 8; ++i) { s += e[i]; ss += e[i] * e[i]; }
    breduce2(s, ss, sred, sred + 4, tid);
    float m = s * (1.0f / 2048.0f);
    float var = ss * (1.0f / 2048.0f) - m * m;
    float rs = rsqrtf(var + 1e-5f);
    int c = tid * 8;
    u16 oo[8];
    #pragma unroll
    for (int i = 0; i < 8; ++i)
        oo[i] = f2b(gelu_exact((e[i] - m) * rs * P[P_LN2W + c + i] + P[P_LN2B + c + i]));
    ushort4 oa, ob;
    oa.x = oo[0]; oa.y = oo[1]; oa.z = oo[2]; oa.w = oo[3];
    ob.x = oo[4]; ob.y = oo[5]; ob.z = oo[6]; ob.w = oo[7];
    ushort4* op = (ushort4*)(A2c + ((size_t)t << 11));
    op[tid * 2] = oa; op[tid * 2 + 1] = ob;
}

// ------------------------------------------------------------------
extern "C" void kernel_launch(void* const* d_in, const int* in_sizes, int n_in,
                              void* d_out, int out_size, void* d_ws, size_t ws_size,
                              hipStream_t stream) {
    (void)in_sizes; (void)n_in; (void)out_size;
    const void* x        = d_in[0];
    const void* conv_w   = d_in[1];
    const void* conv_b   = d_in[2];
    const void* sru_ln_w = d_in[3];
    const void* sru_ln_b = d_in[4];
    const void* sru_W    = d_in[5];
    const void* sru_vf   = d_in[6];
    const void* sru_vr   = d_in[7];
    const void* sru_bf   = d_in[8];
    const void* sru_br   = d_in[9];
    const void* lambda_w = d_in[10];
    const void* rms_w    = d_in[11];
    const void* ln1_w    = d_in[12];
    const void* ln1_b    = d_in[13];
    const void* lin1_w   = d_in[14];
    const void* ln2_w    = d_in[15];
    const void* ln2_b    = d_in[16];
    const void* lin2_w   = d_in[17];
    const void* lin2_b   = d_in[18];

    if (ws_size < WS_REQ) {
        float sv = 1000.0f + (float)(ws_size >> 20);
        k_fill<<<16384, 256, 0, stream>>>((float*)d_out, sv);
        return;
    }

    char* ws = (char*)d_ws;
    u16*   xb    = (u16*)(ws + OFF_XB);
    u16*   cnnb  = (u16*)(ws + OFF_CNNB);
    u16*   xnb   = (u16*)(ws + OFF_XNB);
    u16*   UcA   = (u16*)(ws + OFF_XB);           // 24 MiB; xb dead after conv
    u16*   UcB   = (u16*)(ws + OFF_UCB);          // 24 MiB
    u16*   WcT   = (u16*)(ws + OFF_WCT);
    u16*   WsruT = (u16*)(ws + OFF_WSRUT);
    u16*   W1T   = (u16*)(ws + OFF_W1T);
    u16*   W2T   = (u16*)(ws + OFF_W2T);
    float* carry = (float*)(ws + OFF_CARRY);
    float* P     = (float*)(ws + OFF_P);
    float* scale = (float*)(ws + OFF_SCALE);
    int*   flag  = (int*)(ws + OFF_FLAG);
    float* zbuf  = (float*)(ws + OFF_ZERO);
    const u16* zb16 = (const u16*)zbuf;
    u16*   A1  = xb;                              // Uc dead after last scan
    u16*   T1c = (u16*)(ws + OFF_U4C);            // 32 MiB
    u16*   A2  = cnnb;                            // 64 MiB (2 chunks of 8192 rows)

    k_detect<<<1, 256, 0, stream>>>((const u16*)x, flag);
    k_params<<<64, 256, 0, stream>>>(flag, conv_b, sru_ln_w, sru_ln_b, sru_vf, sru_vr,
                                     sru_bf, sru_br, lambda_w, rms_w, ln1_w, ln1_b,
                                     lin2_b, ln2_w, ln2_b, P, zbuf);
    k_x2b<<<32768, 256, 0, stream>>>(flag, x, xb);
    k_conv_reorder<<<1024, 256, 0, stream>>>(flag, conv_w, WcT);
    // conv: M=32768 N=1024 K=4096 -> 256x8 = 2048 tiles, nn=8
    k_gemm<1, 1><<<2048, 256, 0, stream>>>(xb, WcT, 1024, 4096, 8, 0, 0,
                                           P, nullptr, nullptr, nullptr, flag, zb16, cnnb);
    k_ln<<<32768, 256, 0, stream>>>(cnnb, P, xnb);
    k_transpose_t<<<dim3(48, 16), 256, 0, stream>>>(flag, sru_W, WsruT, 1024, 3072);
    // U chunks (LC=512) fused with previous chunk's scan; nn=24
    k_gemm<2, 2><<<768, 256, 0, stream>>>(xnb, WsruT, 3072, 1024, 24, 0, 0,
                                          P, nullptr, nullptr, nullptr, flag, zb16, UcA);
    for (int ch = 1; ch < NCH; ++ch) {
        u16* cur  = (ch & 1) ? UcB : UcA;
        u16* prev = (ch & 1) ? UcA : UcB;
        k_uscan<<<896, 256, 0, stream>>>(xnb, WsruT, ch * LC, cur, prev, cnnb,
                                         carry, (ch - 1) * LC, ch == 1, P, flag, zb16);
    }
    k_scan<<<dim3(16, 8), 64, 0, stream>>>(UcB, cnnb, xnb, carry, P, (NCH - 1) * LC, 0);
    k_rms_ln1<<<32768, 256, 0, stream>>>(xnb, x, P, flag, scale, A1);
    k_transpose_t<<<dim3(32, 16), 256, 0, stream>>>(flag, lin1_w, W1T, 1024, 2048);
    k_transpose_t<<<dim3(16, 32), 256, 0, stream>>>(flag, lin2_w, W2T, 2048, 1024);
    // FFN: G1+ln2 per 8192-token chunk (nn=16); G2 merged over 16384 tokens (nn=8)
    for (int p = 0; p < 2; ++p) {
        int base = p * 16384;
        for (int h = 0; h < 2; ++h) {
            int tok0 = base + h * MC;
            k_gemm<0, 0><<<1024, 256, 0, stream>>>(A1 + ((size_t)tok0 << 10), W1T, 2048, 1024, 16, 0, 0,
                                                   P, nullptr, nullptr, nullptr, flag, zb16, T1c);
            k_ln2_gelu<<<MC, 256, 0, stream>>>(T1c, P, A2 + ((size_t)(h * MC) << 11));
        }
        // G2: M=16384 N=1024 K=2048 -> 128x8 = 1024 tiles
        k_gemm<0, 3><<<1024, 256, 0, stream>>>(A2, W2T, 1024, 2048, 8, 0, base,
                                               P, xnb, x, scale, flag, zb16, d_out);
    }
}